// Round 1
// baseline (214.814 us; speedup 1.0000x reference)
//
#include <hip/hip_runtime.h>
#include <stdint.h>

typedef unsigned short u16;
typedef __attribute__((ext_vector_type(8))) short bf16x8;
typedef __attribute__((ext_vector_type(4))) float f32x4;

#define NB 8
#define SEQ 1024
#define DDIM 1024
#define NP 128
#define NT 8

__device__ __forceinline__ u16 f2b(float f){
  union { float f; uint32_t u; } v; v.f = f;
  return (u16)((v.u + 0x7FFFu + ((v.u >> 16) & 1u)) >> 16);
}
__device__ __forceinline__ float b2f(u16 h){
  union { uint32_t u; float f; } v; v.u = ((uint32_t)h) << 16; return v.f;
}

__device__ __forceinline__ void load_lds16(const void* g, void* l){
  __builtin_amdgcn_global_load_lds((const __attribute__((address_space(1))) void*)g,
                                   (__attribute__((address_space(3))) void*)l,
                                   16, 0, 0);
}

// ---------------- f32 -> bf16 convert ----------------
__global__ __launch_bounds__(256) void cvt_f32_bf16(const float* __restrict__ src,
                                                    u16* __restrict__ dst, int n){
  int i = blockIdx.x * 256 + threadIdx.x;
  int idx = i * 4;
  if(idx < n){
    float4 v = *(const float4*)(src + idx);
    ushort4 o;
    o.x = f2b(v.x); o.y = f2b(v.y); o.z = f2b(v.z); o.w = f2b(v.w);
    *(ushort4*)(dst + idx) = o;
  }
}

// ---------------- f32 [R][C] -> bf16 [C][R] transpose ----------------
__global__ __launch_bounds__(256) void transpose_w(const float* __restrict__ W,
                                                   u16* __restrict__ Wt,
                                                   int rows, int cols){
  __shared__ float tile[32][33];
  int c0 = blockIdx.x * 32, r0 = blockIdx.y * 32;
  int tx = threadIdx.x;
  for(int i = threadIdx.y; i < 32; i += 8)
    tile[i][tx] = W[(size_t)(r0 + i) * cols + c0 + tx];
  __syncthreads();
  for(int i = threadIdx.y; i < 32; i += 8)
    Wt[(size_t)(c0 + i) * rows + r0 + tx] = f2b(tile[tx][i]);
}

// ---------------- bf16 [b][t][d] -> [b][d][t] transpose ----------------
__global__ __launch_bounds__(256) void transpose_b16(const u16* __restrict__ X,
                                                     u16* __restrict__ Xt){
  __shared__ u16 tile[32][33];
  int b = blockIdx.z;
  const u16* src = X + (size_t)b * SEQ * DDIM;
  u16* dst = Xt + (size_t)b * SEQ * DDIM;
  int d0 = blockIdx.x * 32, t0 = blockIdx.y * 32;
  int tx = threadIdx.x;
  for(int i = threadIdx.y; i < 32; i += 8)
    tile[i][tx] = src[(size_t)(t0 + i) * DDIM + d0 + tx];
  __syncthreads();
  for(int i = threadIdx.y; i < 32; i += 8)
    dst[(size_t)(d0 + i) * SEQ + t0 + tx] = tile[tx][i];
}

// ---------------- bf16 GEMM: C = op(A[M,K] . Bt[N,K]^T + bias) ----------------
// m97-style: 128x128 tile, BK=64, 4 waves (2x2 of 64x64), global_load_lds w=16.
template<bool RELU, bool OUTF32>
__global__ __launch_bounds__(256) void gemm_bt(
    const u16* __restrict__ A, const u16* __restrict__ Bt,
    const float* __restrict__ bias, void* __restrict__ Cv,
    int M, int N, int K, long long bA, long long bB, long long bC)
{
  __shared__ u16 As[128][64];
  __shared__ u16 Bs[128][64];
  const int tid  = threadIdx.x;
  const int lane = tid & 63;
  const int wid  = tid >> 6;
  const int wr = wid >> 1, wc = wid & 1;
  const int bz = blockIdx.z;

  const u16* gA = A + (size_t)bz * bA + (size_t)(blockIdx.x * 128) * K;
  const u16* gB = Bt + (size_t)bz * bB + (size_t)(blockIdx.y * 128) * K;

  f32x4 acc[4][4];
#pragma unroll
  for(int i = 0; i < 4; i++)
#pragma unroll
    for(int j = 0; j < 4; j++){ acc[i][j][0]=0.f; acc[i][j][1]=0.f; acc[i][j][2]=0.f; acc[i][j][3]=0.f; }

  const int srow = tid >> 3;        // 0..31
  const int scol = (tid & 7) * 8;   // element col in tile row

  for(int kt = 0; kt < K; kt += 64){
#pragma unroll
    for(int q = 0; q < 4; q++){
      int row = q * 32 + srow;
      load_lds16(gA + (size_t)row * K + kt + scol, &As[row][scol]);
      load_lds16(gB + (size_t)row * K + kt + scol, &Bs[row][scol]);
    }
    __syncthreads();
    const int fr = lane & 15, kq = lane >> 4;
#pragma unroll
    for(int ks = 0; ks < 2; ks++){
      const int colb = ks * 32 + kq * 8;
      bf16x8 af[4], bfr[4];
#pragma unroll
      for(int mi = 0; mi < 4; mi++) af[mi]  = *(const bf16x8*)&As[wr*64 + mi*16 + fr][colb];
#pragma unroll
      for(int ni = 0; ni < 4; ni++) bfr[ni] = *(const bf16x8*)&Bs[wc*64 + ni*16 + fr][colb];
#pragma unroll
      for(int mi = 0; mi < 4; mi++)
#pragma unroll
        for(int ni = 0; ni < 4; ni++)
          acc[mi][ni] = __builtin_amdgcn_mfma_f32_16x16x32_bf16(af[mi], bfr[ni], acc[mi][ni], 0, 0, 0);
    }
    __syncthreads();
  }

  // epilogue: C/D layout col=lane&15, row=(lane>>4)*4+reg
  const int m0 = blockIdx.x * 128 + wr * 64;
  const int n0 = blockIdx.y * 128 + wc * 64;
  const int fr = lane & 15, rq = lane >> 4;
#pragma unroll
  for(int ni = 0; ni < 4; ni++){
    const int gcol = n0 + ni * 16 + fr;
    const float bv = bias ? bias[gcol] : 0.f;
#pragma unroll
    for(int mi = 0; mi < 4; mi++){
#pragma unroll
      for(int r = 0; r < 4; r++){
        const int grow = m0 + mi * 16 + rq * 4 + r;
        float v = acc[mi][ni][r] + bv;
        if(RELU) v = fmaxf(v, 0.f);
        if(OUTF32)
          ((float*)Cv)[(size_t)bz * bC + (size_t)grow * N + gcol] = v;
        else
          ((u16*)Cv)[(size_t)bz * bC + (size_t)grow * N + gcol] = f2b(v);
      }
    }
  }
}

// ---------------- row softmax: f32 [8192][1024] -> bf16 probs ----------------
__global__ __launch_bounds__(256) void softmax_rows(const float* __restrict__ Sc,
                                                    u16* __restrict__ Pb){
  __shared__ float red[8];
  const int row = blockIdx.x;
  const int tid = threadIdx.x;
  const float* src = Sc + (size_t)row * 1024;
  float4 v = *(const float4*)(src + tid * 4);
  float m = fmaxf(fmaxf(v.x, v.y), fmaxf(v.z, v.w));
#pragma unroll
  for(int off = 32; off; off >>= 1) m = fmaxf(m, __shfl_xor(m, off));
  if((tid & 63) == 0) red[tid >> 6] = m;
  __syncthreads();
  m = fmaxf(fmaxf(red[0], red[1]), fmaxf(red[2], red[3]));
  float e0 = __expf(v.x - m), e1 = __expf(v.y - m), e2 = __expf(v.z - m), e3 = __expf(v.w - m);
  float s = e0 + e1 + e2 + e3;
#pragma unroll
  for(int off = 32; off; off >>= 1) s += __shfl_xor(s, off);
  if((tid & 63) == 0) red[4 + (tid >> 6)] = s;
  __syncthreads();
  s = red[4] + red[5] + red[6] + red[7];
  const float inv = 1.f / s;
  ushort4 o;
  o.x = f2b(e0 * inv); o.y = f2b(e1 * inv); o.z = f2b(e2 * inv); o.w = f2b(e3 * inv);
  *(ushort4*)(Pb + (size_t)row * 1024 + tid * 4) = o;
}

// ---------------- em = [p_cla | out2] @ W_hid + b_hid ----------------
__global__ __launch_bounds__(256) void em_kernel(const u16* __restrict__ out2,
                                                 const float* __restrict__ pcla,
                                                 const float* __restrict__ Whid,
                                                 const float* __restrict__ bhid,
                                                 float* __restrict__ em){
  const int row  = blockIdx.x * 4 + (threadIdx.x >> 6);
  const int lane = threadIdx.x & 63;
  float s[8] = {0.f,0.f,0.f,0.f,0.f,0.f,0.f,0.f};
  const u16* o2 = out2 + (size_t)row * 1024 + lane * 16;
#pragma unroll
  for(int h = 0; h < 2; h++){
    bf16x8 v = *(const bf16x8*)(o2 + h * 8);
#pragma unroll
    for(int e = 0; e < 8; e++){
      const float od = b2f((u16)v[e]);
      const int d = lane * 16 + h * 8 + e;
      const float* wr = Whid + (size_t)(NP + d) * 8;
#pragma unroll
      for(int j = 0; j < 8; j++) s[j] += od * wr[j];
    }
  }
#pragma unroll
  for(int q = 0; q < 2; q++){
    const int p = lane * 2 + q;
    const float pv = pcla[(size_t)row * NP + p];
    const float* wr = Whid + (size_t)p * 8;
#pragma unroll
    for(int j = 0; j < 8; j++) s[j] += pv * wr[j];
  }
#pragma unroll
  for(int off = 1; off < 64; off <<= 1)
#pragma unroll
    for(int j = 0; j < 8; j++) s[j] += __shfl_xor(s[j], off);
  if(lane == 0){
#pragma unroll
    for(int j = 0; j < 8; j++) em[(size_t)row * 8 + j] = s[j] + bhid[j];
  }
}

// ---------------- CRF NLL per batch (prob-domain chunked scan + tree) ----------------
__global__ __launch_bounds__(256) void crf_kernel(const float* __restrict__ em,
                                                  const int* __restrict__ tags,
                                                  const float* __restrict__ cstart,
                                                  const float* __restrict__ cend,
                                                  const float* __restrict__ ctrans,
                                                  float* __restrict__ partial){
  const int b = blockIdx.x;
  const int tid = threadIdx.x;
  const float* emb = em + (size_t)b * SEQ * 8;
  const int* tg = tags + b * SEQ;

  __shared__ float Mbuf[128][64];
  __shared__ float Mbuf2[64][64];
  __shared__ float ls1[128], ls2[64];
  __shared__ float etr_s[64];
  __shared__ float mxs[64];
  __shared__ float red[256];

  if(tid < 64) etr_s[tid] = expf(ctrans[tid]);

  // ---- num (tag path score) ----
  float loc = 0.f;
  for(int t = tid; t < SEQ; t += 256){
    const int tgt = tg[t];
    loc += emb[t * 8 + tgt];
    if(t < SEQ - 1) loc += ctrans[tgt * 8 + tg[t + 1]];
  }
  if(tid == 0) loc += cstart[tg[0]] + cend[tg[SEQ - 1]];
  red[tid] = loc;
  __syncthreads();
  for(int s = 128; s > 0; s >>= 1){
    if(tid < s) red[tid] += red[tid + s];
    __syncthreads();
  }
  // red[0] = num; preserved below.

  // ---- per-chunk matrix products (prob domain) ----
  // M_t[i][j] = exp(trans[i][j]) * exp(em[t][j]), t = 1..1023.
  // chunk 0: t=1..7 ; chunk c>=1: t=8c..8c+7.
  if(tid < 128){
    const int c = tid;
    const int t0 = (c == 0) ? 1 : c * 8;
    const int t1 = c * 8 + 8;
    float etr[64];
#pragma unroll
    for(int i = 0; i < 64; i++) etr[i] = etr_s[i];
    float acc[64];
    float ej[8];
#pragma unroll
    for(int j = 0; j < 8; j++) ej[j] = expf(emb[t0 * 8 + j]);
#pragma unroll
    for(int i = 0; i < 8; i++)
#pragma unroll
      for(int j = 0; j < 8; j++) acc[i * 8 + j] = etr[i * 8 + j] * ej[j];
    for(int t = t0 + 1; t < t1; t++){
#pragma unroll
      for(int j = 0; j < 8; j++) ej[j] = expf(emb[t * 8 + j]);
#pragma unroll
      for(int i = 0; i < 8; i++){
        float tmp[8];
#pragma unroll
        for(int j = 0; j < 8; j++){
          float sv = 0.f;
#pragma unroll
          for(int k = 0; k < 8; k++) sv += acc[i * 8 + k] * etr[k * 8 + j];
          tmp[j] = sv * ej[j];
        }
#pragma unroll
        for(int j = 0; j < 8; j++) acc[i * 8 + j] = tmp[j];
      }
    }
    float mx = acc[0];
#pragma unroll
    for(int i = 1; i < 64; i++) mx = fmaxf(mx, acc[i]);
    const float im = 1.f / mx;
#pragma unroll
    for(int i = 0; i < 64; i++) Mbuf[c][i] = acc[i] * im;
    ls1[c] = logf(mx);
  }
  __syncthreads();

  // ---- tree combine: 128 -> 1 ----
  float* src = &Mbuf[0][0];  float* dst = &Mbuf2[0][0];
  float* lsrc = ls1;         float* ldst = ls2;
  for(int n = 64; n >= 1; n >>= 1){
    for(int idx = tid; idx < n * 64; idx += 256){
      const int p = idx >> 6, e = idx & 63, i = e >> 3, j = e & 7;
      const float* Am = src + (size_t)(2 * p) * 64;
      const float* Bm = src + (size_t)(2 * p + 1) * 64;
      float sv = 0.f;
#pragma unroll
      for(int k = 0; k < 8; k++) sv += Am[i * 8 + k] * Bm[k * 8 + j];
      dst[(size_t)p * 64 + e] = sv;
    }
    __syncthreads();
    if(tid < n){
      const float* Cm = dst + (size_t)tid * 64;
      float mx = Cm[0];
#pragma unroll
      for(int i = 1; i < 64; i++) mx = fmaxf(mx, Cm[i]);
      mxs[tid] = 1.f / mx;
      ldst[tid] = lsrc[2 * tid] + lsrc[2 * tid + 1] + logf(mx);
    }
    __syncthreads();
    for(int idx = tid; idx < n * 64; idx += 256)
      dst[idx] *= mxs[idx >> 6];
    __syncthreads();
    float* tf = src; src = dst; dst = tf;
    float* tl = lsrc; lsrc = ldst; ldst = tl;
  }

  if(tid == 0){
    float a0[8];
#pragma unroll
    for(int i = 0; i < 8; i++) a0[i] = expf(cstart[i] + emb[i]);
    float z = 0.f;
#pragma unroll
    for(int j = 0; j < 8; j++){
      float t = 0.f;
#pragma unroll
      for(int i = 0; i < 8; i++) t += a0[i] * src[i * 8 + j];
      z += t * expf(cend[j]);
    }
    const float logZ = logf(z) + lsrc[0];
    partial[b] = logZ - red[0];
  }
}

__global__ void final_sum(const float* __restrict__ partial, float* __restrict__ out){
  if(threadIdx.x == 0){
    float s = 0.f;
    for(int b = 0; b < NB; b++) s += partial[b];
    out[0] = s;
  }
}

// ---------------- launch ----------------
extern "C" void kernel_launch(void* const* d_in, const int* in_sizes, int n_in,
                              void* d_out, int out_size, void* d_ws, size_t ws_size,
                              hipStream_t stream){
  (void)in_sizes; (void)n_in; (void)out_size; (void)ws_size;
  const float* x      = (const float*)d_in[0];
  const float* p_cla  = (const float*)d_in[1];
  const float* W_emo  = (const float*)d_in[2];
  const float* b_emo  = (const float*)d_in[3];
  const float* W_att  = (const float*)d_in[4];
  const float* b_att  = (const float*)d_in[5];
  const float* W_hid  = (const float*)d_in[6];
  const float* b_hid  = (const float*)d_in[7];
  const float* cstart = (const float*)d_in[8];
  const float* cend   = (const float*)d_in[9];
  const float* ctrans = (const float*)d_in[10];
  const int*   tags   = (const int*)d_in[11];

  char* ws = (char*)d_ws;
  const size_t MB = 1u << 20;
  u16*   xb     = (u16*)(ws + 0 * MB);        // 16MB; reused as p_b after GEMM1
  u16*   p_b    = xb;
  u16*   wemoT  = (u16*)(ws + 16 * MB);       // 2MB
  u16*   wattT  = (u16*)(ws + 18 * MB);       // 2MB
  u16*   out_b  = (u16*)(ws + 20 * MB);       // 16MB
  u16*   outT   = (u16*)(ws + 36 * MB);       // 16MB
  u16*   oatt   = (u16*)(ws + 52 * MB);       // 16MB
  float* scores = (float*)(ws + 68 * MB);     // 32MB
  u16*   out2   = (u16*)(ws + 100 * MB);      // 16MB
  float* em     = (float*)(ws + 116 * MB);    // 256KB
  float* part   = (float*)(ws + 116 * MB + 262144);

  const long long bs = (long long)SEQ * DDIM;

  cvt_f32_bf16<<<8192, 256, 0, stream>>>(x, xb, NB * SEQ * DDIM);
  transpose_w<<<dim3(32, 32), dim3(32, 8), 0, stream>>>(W_emo, wemoT, DDIM, DDIM);
  transpose_w<<<dim3(32, 32), dim3(32, 8), 0, stream>>>(W_att, wattT, DDIM, DDIM);

  // out = relu(x @ W_emo + b_emo)
  gemm_bt<true, false><<<dim3(64, 8, 1), 256, 0, stream>>>(
      xb, wemoT, b_emo, out_b, NB * SEQ, DDIM, DDIM, 0, 0, 0);
  // V^T for PV
  transpose_b16<<<dim3(32, 32, NB), dim3(32, 8), 0, stream>>>(out_b, outT);
  // out_att = out @ W_att + b_att
  gemm_bt<false, false><<<dim3(64, 8, 1), 256, 0, stream>>>(
      out_b, wattT, b_att, oatt, NB * SEQ, DDIM, DDIM, 0, 0, 0);
  // scores[b] = out_att[b] @ out[b]^T  (f32)
  gemm_bt<false, true><<<dim3(8, 8, NB), 256, 0, stream>>>(
      oatt, out_b, nullptr, scores, SEQ, SEQ, DDIM, bs, bs, bs);
  // att = softmax(scores) -> bf16
  softmax_rows<<<NB * SEQ, 256, 0, stream>>>(scores, p_b);
  // out2[b] = att[b] @ out[b]
  gemm_bt<false, false><<<dim3(8, 8, NB), 256, 0, stream>>>(
      p_b, outT, nullptr, out2, SEQ, SEQ, DDIM, bs, bs, bs);
  // em = [p_cla | out2] @ W_hid + b_hid
  em_kernel<<<2048, 256, 0, stream>>>(out2, p_cla, W_hid, b_hid, em);
  // CRF NLL
  crf_kernel<<<NB, 256, 0, stream>>>(em, tags, cstart, cend, ctrans, part);
  final_sum<<<1, 64, 0, stream>>>(part, (float*)d_out);
}

// Round 2
// 202.692 us; speedup vs baseline: 1.0598x; 1.0598x over previous
//
#include <hip/hip_runtime.h>
#include <stdint.h>

typedef unsigned short u16;
typedef __attribute__((ext_vector_type(8))) short bf16x8;
typedef __attribute__((ext_vector_type(4))) float f32x4;

#define NB 8
#define SEQ 1024
#define DDIM 1024
#define NP 128
#define NT 8

__device__ __forceinline__ u16 f2b(float f){
  union { float f; uint32_t u; } v; v.f = f;
  return (u16)((v.u + 0x7FFFu + ((v.u >> 16) & 1u)) >> 16);
}
__device__ __forceinline__ float b2f(u16 h){
  union { uint32_t u; float f; } v; v.u = ((uint32_t)h) << 16; return v.f;
}

__device__ __forceinline__ void load_lds16(const void* g, void* l){
  __builtin_amdgcn_global_load_lds((const __attribute__((address_space(1))) void*)g,
                                   (__attribute__((address_space(3))) void*)l,
                                   16, 0, 0);
}

// ---------------- f32 -> bf16 convert ----------------
__global__ __launch_bounds__(256) void cvt_f32_bf16(const float* __restrict__ src,
                                                    u16* __restrict__ dst, int n){
  int i = blockIdx.x * 256 + threadIdx.x;
  int idx = i * 4;
  if(idx < n){
    float4 v = *(const float4*)(src + idx);
    ushort4 o;
    o.x = f2b(v.x); o.y = f2b(v.y); o.z = f2b(v.z); o.w = f2b(v.w);
    *(ushort4*)(dst + idx) = o;
  }
}

// ------- f32 [1024][1024] -> bf16 [1024][1024]^T for both weights; also zero rowsum -------
__global__ __launch_bounds__(256) void transpose_w2(const float* __restrict__ W0,
                                                    const float* __restrict__ W1,
                                                    u16* __restrict__ T0,
                                                    u16* __restrict__ T1,
                                                    float* __restrict__ rowsum){
  __shared__ float tile[32][33];
  const float* W = blockIdx.z ? W1 : W0;
  u16* Wt = blockIdx.z ? T1 : T0;
  int c0 = blockIdx.x * 32, r0 = blockIdx.y * 32;
  int tx = threadIdx.x;
  for(int i = threadIdx.y; i < 32; i += 8)
    tile[i][tx] = W[(size_t)(r0 + i) * DDIM + c0 + tx];
  __syncthreads();
  for(int i = threadIdx.y; i < 32; i += 8)
    Wt[(size_t)(c0 + i) * DDIM + r0 + tx] = f2b(tile[tx][i]);
  if(blockIdx.z == 0 && blockIdx.y == 0){
    int i = blockIdx.x * 256 + threadIdx.y * 32 + tx;
    rowsum[i] = 0.f;
  }
}

// ---------------- bf16 [b][t][d] -> [b][d][t] transpose ----------------
__global__ __launch_bounds__(256) void transpose_b16(const u16* __restrict__ X,
                                                     u16* __restrict__ Xt){
  __shared__ u16 tile[32][33];
  int b = blockIdx.z;
  const u16* src = X + (size_t)b * SEQ * DDIM;
  u16* dst = Xt + (size_t)b * SEQ * DDIM;
  int d0 = blockIdx.x * 32, t0 = blockIdx.y * 32;
  int tx = threadIdx.x;
  for(int i = threadIdx.y; i < 32; i += 8)
    tile[i][tx] = src[(size_t)(t0 + i) * DDIM + d0 + tx];
  __syncthreads();
  for(int i = threadIdx.y; i < 32; i += 8)
    dst[(size_t)(d0 + i) * SEQ + t0 + tx] = tile[tx][i];
}

// ---------------- bf16 GEMM: C = epilogue(A[M,K] . Bt[N,K]^T) ----------------
// MODE 0: C = [relu](acc + bias)           -> bf16
// MODE 1: C = exp(acc) -> bf16, rowsum[row] += sum_cols exp(acc)  (atomic)
// MODE 2: C = acc * (1/rowsum[row])        -> bf16
template<int MODE, bool RELU>
__global__ __launch_bounds__(256) void gemm_bt(
    const u16* __restrict__ A, const u16* __restrict__ Bt,
    const float* __restrict__ bias, float* __restrict__ rowsum,
    u16* __restrict__ Cv,
    int M, int N, int K, long long bA, long long bB, long long bC)
{
  __shared__ u16 As[128][64];
  __shared__ u16 Bs[128][64];
  const int tid  = threadIdx.x;
  const int lane = tid & 63;
  const int wid  = tid >> 6;
  const int wr = wid >> 1, wc = wid & 1;
  const int bz = blockIdx.z;

  const u16* gA = A + (size_t)bz * bA + (size_t)(blockIdx.x * 128) * K;
  const u16* gB = Bt + (size_t)bz * bB + (size_t)(blockIdx.y * 128) * K;

  f32x4 acc[4][4];
#pragma unroll
  for(int i = 0; i < 4; i++)
#pragma unroll
    for(int j = 0; j < 4; j++){ acc[i][j][0]=0.f; acc[i][j][1]=0.f; acc[i][j][2]=0.f; acc[i][j][3]=0.f; }

  const int srow = tid >> 3;        // 0..31
  const int scol = (tid & 7) * 8;   // element col in tile row

  for(int kt = 0; kt < K; kt += 64){
#pragma unroll
    for(int q = 0; q < 4; q++){
      int row = q * 32 + srow;
      load_lds16(gA + (size_t)row * K + kt + scol, &As[row][scol]);
      load_lds16(gB + (size_t)row * K + kt + scol, &Bs[row][scol]);
    }
    __syncthreads();
    const int fr = lane & 15, kq = lane >> 4;
#pragma unroll
    for(int ks = 0; ks < 2; ks++){
      const int colb = ks * 32 + kq * 8;
      bf16x8 af[4], bfr[4];
#pragma unroll
      for(int mi = 0; mi < 4; mi++) af[mi]  = *(const bf16x8*)&As[wr*64 + mi*16 + fr][colb];
#pragma unroll
      for(int ni = 0; ni < 4; ni++) bfr[ni] = *(const bf16x8*)&Bs[wc*64 + ni*16 + fr][colb];
#pragma unroll
      for(int mi = 0; mi < 4; mi++)
#pragma unroll
        for(int ni = 0; ni < 4; ni++)
          acc[mi][ni] = __builtin_amdgcn_mfma_f32_16x16x32_bf16(af[mi], bfr[ni], acc[mi][ni], 0, 0, 0);
    }
    __syncthreads();
  }

  // epilogue: C/D layout col=lane&15, row=(lane>>4)*4+reg
  const int m0 = blockIdx.x * 128 + wr * 64;
  const int n0 = blockIdx.y * 128 + wc * 64;
  const int fr = lane & 15, rq = lane >> 4;

  if(MODE == 0){
#pragma unroll
    for(int ni = 0; ni < 4; ni++){
      const int gcol = n0 + ni * 16 + fr;
      const float bv = bias[gcol];
#pragma unroll
      for(int mi = 0; mi < 4; mi++){
#pragma unroll
        for(int r = 0; r < 4; r++){
          const int grow = m0 + mi * 16 + rq * 4 + r;
          float v = acc[mi][ni][r] + bv;
          if(RELU) v = fmaxf(v, 0.f);
          Cv[(size_t)bz * bC + (size_t)grow * N + gcol] = f2b(v);
        }
      }
    }
  } else if(MODE == 1){
    float rs[4][4];
#pragma unroll
    for(int mi = 0; mi < 4; mi++)
#pragma unroll
      for(int r = 0; r < 4; r++) rs[mi][r] = 0.f;
#pragma unroll
    for(int ni = 0; ni < 4; ni++){
      const int gcol = n0 + ni * 16 + fr;
#pragma unroll
      for(int mi = 0; mi < 4; mi++){
#pragma unroll
        for(int r = 0; r < 4; r++){
          const int grow = m0 + mi * 16 + rq * 4 + r;
          float e = __expf(acc[mi][ni][r]);
          rs[mi][r] += e;
          Cv[(size_t)bz * bC + (size_t)grow * N + gcol] = f2b(e);
        }
      }
    }
    // reduce over the 16 fr-lanes (col groups), then one atomic per row
#pragma unroll
    for(int off = 1; off < 16; off <<= 1)
#pragma unroll
      for(int mi = 0; mi < 4; mi++)
#pragma unroll
        for(int r = 0; r < 4; r++) rs[mi][r] += __shfl_xor(rs[mi][r], off);
    if(fr == 0){
#pragma unroll
      for(int mi = 0; mi < 4; mi++)
#pragma unroll
        for(int r = 0; r < 4; r++){
          const int grow = m0 + mi * 16 + rq * 4 + r;
          atomicAdd(&rowsum[bz * SEQ + grow], rs[mi][r]);
        }
    }
  } else {
    float inv[4][4];
#pragma unroll
    for(int mi = 0; mi < 4; mi++)
#pragma unroll
      for(int r = 0; r < 4; r++){
        const int grow = m0 + mi * 16 + rq * 4 + r;
        inv[mi][r] = __builtin_amdgcn_rcpf(rowsum[bz * SEQ + grow]);
      }
#pragma unroll
    for(int ni = 0; ni < 4; ni++){
      const int gcol = n0 + ni * 16 + fr;
#pragma unroll
      for(int mi = 0; mi < 4; mi++){
#pragma unroll
        for(int r = 0; r < 4; r++){
          const int grow = m0 + mi * 16 + rq * 4 + r;
          Cv[(size_t)bz * bC + (size_t)grow * N + gcol] = f2b(acc[mi][ni][r] * inv[mi][r]);
        }
      }
    }
  }
}

// ---------------- em = [p_cla | out2] @ W_hid + b_hid ----------------
__global__ __launch_bounds__(256) void em_kernel(const u16* __restrict__ out2,
                                                 const float* __restrict__ pcla,
                                                 const float* __restrict__ Whid,
                                                 const float* __restrict__ bhid,
                                                 float* __restrict__ em){
  const int row  = blockIdx.x * 4 + (threadIdx.x >> 6);
  const int lane = threadIdx.x & 63;
  float s[8] = {0.f,0.f,0.f,0.f,0.f,0.f,0.f,0.f};
  const u16* o2 = out2 + (size_t)row * 1024 + lane * 16;
#pragma unroll
  for(int h = 0; h < 2; h++){
    bf16x8 v = *(const bf16x8*)(o2 + h * 8);
#pragma unroll
    for(int e = 0; e < 8; e++){
      const float od = b2f((u16)v[e]);
      const int d = lane * 16 + h * 8 + e;
      const float* wr = Whid + (size_t)(NP + d) * 8;
#pragma unroll
      for(int j = 0; j < 8; j++) s[j] += od * wr[j];
    }
  }
#pragma unroll
  for(int q = 0; q < 2; q++){
    const int p = lane * 2 + q;
    const float pv = pcla[(size_t)row * NP + p];
    const float* wr = Whid + (size_t)p * 8;
#pragma unroll
    for(int j = 0; j < 8; j++) s[j] += pv * wr[j];
  }
#pragma unroll
  for(int off = 1; off < 64; off <<= 1)
#pragma unroll
    for(int j = 0; j < 8; j++) s[j] += __shfl_xor(s[j], off);
  if(lane == 0){
#pragma unroll
    for(int j = 0; j < 8; j++) em[(size_t)row * 8 + j] = s[j] + bhid[j];
  }
}

// ---------------- CRF NLL per batch (prob-domain chunked scan + tree) ----------------
__global__ __launch_bounds__(256) void crf_kernel(const float* __restrict__ em,
                                                  const int* __restrict__ tags,
                                                  const float* __restrict__ cstart,
                                                  const float* __restrict__ cend,
                                                  const float* __restrict__ ctrans,
                                                  float* __restrict__ partial){
  const int b = blockIdx.x;
  const int tid = threadIdx.x;
  const float* emb = em + (size_t)b * SEQ * 8;
  const int* tg = tags + b * SEQ;

  __shared__ float Mbuf[128][64];
  __shared__ float Mbuf2[64][64];
  __shared__ float ls1[128], ls2[64];
  __shared__ float etr_s[64];
  __shared__ float mxs[64];
  __shared__ float red[256];

  if(tid < 64) etr_s[tid] = expf(ctrans[tid]);

  // ---- num (tag path score) ----
  float loc = 0.f;
  for(int t = tid; t < SEQ; t += 256){
    const int tgt = tg[t];
    loc += emb[t * 8 + tgt];
    if(t < SEQ - 1) loc += ctrans[tgt * 8 + tg[t + 1]];
  }
  if(tid == 0) loc += cstart[tg[0]] + cend[tg[SEQ - 1]];
  red[tid] = loc;
  __syncthreads();
  for(int s = 128; s > 0; s >>= 1){
    if(tid < s) red[tid] += red[tid + s];
    __syncthreads();
  }

  // ---- per-chunk matrix products (prob domain) ----
  if(tid < 128){
    const int c = tid;
    const int t0 = (c == 0) ? 1 : c * 8;
    const int t1 = c * 8 + 8;
    float etr[64];
#pragma unroll
    for(int i = 0; i < 64; i++) etr[i] = etr_s[i];
    float acc[64];
    float ej[8];
#pragma unroll
    for(int j = 0; j < 8; j++) ej[j] = expf(emb[t0 * 8 + j]);
#pragma unroll
    for(int i = 0; i < 8; i++)
#pragma unroll
      for(int j = 0; j < 8; j++) acc[i * 8 + j] = etr[i * 8 + j] * ej[j];
    for(int t = t0 + 1; t < t1; t++){
#pragma unroll
      for(int j = 0; j < 8; j++) ej[j] = expf(emb[t * 8 + j]);
#pragma unroll
      for(int i = 0; i < 8; i++){
        float tmp[8];
#pragma unroll
        for(int j = 0; j < 8; j++){
          float sv = 0.f;
#pragma unroll
          for(int k = 0; k < 8; k++) sv += acc[i * 8 + k] * etr[k * 8 + j];
          tmp[j] = sv * ej[j];
        }
#pragma unroll
        for(int j = 0; j < 8; j++) acc[i * 8 + j] = tmp[j];
      }
    }
    float mx = acc[0];
#pragma unroll
    for(int i = 1; i < 64; i++) mx = fmaxf(mx, acc[i]);
    const float im = 1.f / mx;
#pragma unroll
    for(int i = 0; i < 64; i++) Mbuf[c][i] = acc[i] * im;
    ls1[c] = logf(mx);
  }
  __syncthreads();

  // ---- tree combine: 128 -> 1 ----
  float* src = &Mbuf[0][0];  float* dst = &Mbuf2[0][0];
  float* lsrc = ls1;         float* ldst = ls2;
  for(int n = 64; n >= 1; n >>= 1){
    for(int idx = tid; idx < n * 64; idx += 256){
      const int p = idx >> 6, e = idx & 63, i = e >> 3, j = e & 7;
      const float* Am = src + (size_t)(2 * p) * 64;
      const float* Bm = src + (size_t)(2 * p + 1) * 64;
      float sv = 0.f;
#pragma unroll
      for(int k = 0; k < 8; k++) sv += Am[i * 8 + k] * Bm[k * 8 + j];
      dst[(size_t)p * 64 + e] = sv;
    }
    __syncthreads();
    if(tid < n){
      const float* Cm = dst + (size_t)tid * 64;
      float mx = Cm[0];
#pragma unroll
      for(int i = 1; i < 64; i++) mx = fmaxf(mx, Cm[i]);
      mxs[tid] = 1.f / mx;
      ldst[tid] = lsrc[2 * tid] + lsrc[2 * tid + 1] + logf(mx);
    }
    __syncthreads();
    for(int idx = tid; idx < n * 64; idx += 256)
      dst[idx] *= mxs[idx >> 6];
    __syncthreads();
    float* tf = src; src = dst; dst = tf;
    float* tl = lsrc; lsrc = ldst; ldst = tl;
  }

  if(tid == 0){
    float a0[8];
#pragma unroll
    for(int i = 0; i < 8; i++) a0[i] = expf(cstart[i] + emb[i]);
    float z = 0.f;
#pragma unroll
    for(int j = 0; j < 8; j++){
      float t = 0.f;
#pragma unroll
      for(int i = 0; i < 8; i++) t += a0[i] * src[i * 8 + j];
      z += t * expf(cend[j]);
    }
    const float logZ = logf(z) + lsrc[0];
    partial[b] = logZ - red[0];
  }
}

__global__ void final_sum(const float* __restrict__ partial, float* __restrict__ out){
  if(threadIdx.x == 0){
    float s = 0.f;
    for(int b = 0; b < NB; b++) s += partial[b];
    out[0] = s;
  }
}

// ---------------- launch ----------------
extern "C" void kernel_launch(void* const* d_in, const int* in_sizes, int n_in,
                              void* d_out, int out_size, void* d_ws, size_t ws_size,
                              hipStream_t stream){
  (void)in_sizes; (void)n_in; (void)out_size; (void)ws_size;
  const float* x      = (const float*)d_in[0];
  const float* p_cla  = (const float*)d_in[1];
  const float* W_emo  = (const float*)d_in[2];
  const float* b_emo  = (const float*)d_in[3];
  const float* W_att  = (const float*)d_in[4];
  const float* b_att  = (const float*)d_in[5];
  const float* W_hid  = (const float*)d_in[6];
  const float* b_hid  = (const float*)d_in[7];
  const float* cstart = (const float*)d_in[8];
  const float* cend   = (const float*)d_in[9];
  const float* ctrans = (const float*)d_in[10];
  const int*   tags   = (const int*)d_in[11];

  char* ws = (char*)d_ws;
  const size_t MB = 1u << 20;
  u16*   xb     = (u16*)(ws + 0 * MB);        // 16MB
  u16*   wemoT  = (u16*)(ws + 16 * MB);       // 2MB
  u16*   wattT  = (u16*)(ws + 18 * MB);       // 2MB
  u16*   out_b  = (u16*)(ws + 20 * MB);       // 16MB
  u16*   outT   = (u16*)(ws + 36 * MB);       // 16MB
  u16*   oatt   = (u16*)(ws + 52 * MB);       // 16MB
  u16*   scores = (u16*)(ws + 68 * MB);       // 16MB (unnormalized exp, bf16)
  u16*   out2   = (u16*)(ws + 84 * MB);       // 16MB
  float* em     = (float*)(ws + 100 * MB);    // 256KB
  float* part   = (float*)(ws + 100 * MB + 262144);
  float* rowsum = (float*)(ws + 100 * MB + 524288);  // 32KB

  const long long bs = (long long)SEQ * DDIM;

  cvt_f32_bf16<<<8192, 256, 0, stream>>>(x, xb, NB * SEQ * DDIM);
  transpose_w2<<<dim3(32, 32, 2), dim3(32, 8), 0, stream>>>(W_emo, W_att, wemoT, wattT, rowsum);

  // out = relu(x @ W_emo + b_emo)
  gemm_bt<0, true><<<dim3(64, 8, 1), 256, 0, stream>>>(
      xb, wemoT, b_emo, nullptr, out_b, NB * SEQ, DDIM, DDIM, 0, 0, 0);
  // V^T for PV
  transpose_b16<<<dim3(32, 32, NB), dim3(32, 8), 0, stream>>>(out_b, outT);
  // out_att = out @ W_att + b_att
  gemm_bt<0, false><<<dim3(64, 8, 1), 256, 0, stream>>>(
      out_b, wattT, b_att, nullptr, oatt, NB * SEQ, DDIM, DDIM, 0, 0, 0);
  // scores[b] = exp(out_att[b] @ out[b]^T) (bf16, unnormalized) + rowsum atomics
  gemm_bt<1, false><<<dim3(8, 8, NB), 256, 0, stream>>>(
      oatt, out_b, nullptr, rowsum, scores, SEQ, SEQ, DDIM, bs, bs, bs);
  // out2[b] = (scores[b] @ out[b]) / rowsum  (softmax normalization folded in)
  gemm_bt<2, false><<<dim3(8, 8, NB), 256, 0, stream>>>(
      scores, outT, nullptr, rowsum, out2, SEQ, SEQ, DDIM, bs, bs, bs);
  // em = [p_cla | out2] @ W_hid + b_hid
  em_kernel<<<2048, 256, 0, stream>>>(out2, p_cla, W_hid, b_hid, em);
  // CRF NLL
  crf_kernel<<<NB, 256, 0, stream>>>(em, tags, cstart, cend, ctrans, part);
  final_sum<<<1, 64, 0, stream>>>(part, (float*)d_out);
}

// Round 3
// 193.078 us; speedup vs baseline: 1.1126x; 1.0498x over previous
//
#include <hip/hip_runtime.h>
#include <stdint.h>

typedef unsigned short u16;
typedef __attribute__((ext_vector_type(8))) short bf16x8;
typedef __attribute__((ext_vector_type(4))) float f32x4;

#define NB 8
#define SEQ 1024
#define DDIM 1024
#define NP 128
#define NT 8

__device__ __forceinline__ u16 f2b(float f){
  union { float f; uint32_t u; } v; v.f = f;
  return (u16)((v.u + 0x7FFFu + ((v.u >> 16) & 1u)) >> 16);
}
__device__ __forceinline__ float b2f(u16 h){
  union { uint32_t u; float f; } v; v.u = ((uint32_t)h) << 16; return v.f;
}

__device__ __forceinline__ void load_lds16(const void* g, void* l){
  __builtin_amdgcn_global_load_lds((const __attribute__((address_space(1))) void*)g,
                                   (__attribute__((address_space(3))) void*)l,
                                   16, 0, 0);
}

#define MEMFENCE asm volatile("" ::: "memory")
#define SBAR() do { MEMFENCE; __builtin_amdgcn_s_barrier(); MEMFENCE; } while(0)

// ---------------- f32 -> bf16 convert ----------------
__global__ __launch_bounds__(256) void cvt_f32_bf16(const float* __restrict__ src,
                                                    u16* __restrict__ dst, int n){
  int i = blockIdx.x * 256 + threadIdx.x;
  int idx = i * 4;
  if(idx < n){
    float4 v = *(const float4*)(src + idx);
    ushort4 o;
    o.x = f2b(v.x); o.y = f2b(v.y); o.z = f2b(v.z); o.w = f2b(v.w);
    *(ushort4*)(dst + idx) = o;
  }
}

// ------- f32 [1024][1024] -> bf16 transpose for both weights; also zero rowsum -------
__global__ __launch_bounds__(256) void transpose_w2(const float* __restrict__ W0,
                                                    const float* __restrict__ W1,
                                                    u16* __restrict__ T0,
                                                    u16* __restrict__ T1,
                                                    float* __restrict__ rowsum){
  __shared__ float tile[32][33];
  const float* W = blockIdx.z ? W1 : W0;
  u16* Wt = blockIdx.z ? T1 : T0;
  int c0 = blockIdx.x * 32, r0 = blockIdx.y * 32;
  int tx = threadIdx.x;
  for(int i = threadIdx.y; i < 32; i += 8)
    tile[i][tx] = W[(size_t)(r0 + i) * DDIM + c0 + tx];
  __syncthreads();
  for(int i = threadIdx.y; i < 32; i += 8)
    Wt[(size_t)(c0 + i) * DDIM + r0 + tx] = f2b(tile[tx][i]);
  if(blockIdx.z == 0 && blockIdx.y == 0){
    int i = blockIdx.x * 256 + threadIdx.y * 32 + tx;
    rowsum[i] = 0.f;
  }
}

// ---------------- bf16 [b][t][d] -> [b][d][t] transpose ----------------
__global__ __launch_bounds__(256) void transpose_b16(const u16* __restrict__ X,
                                                     u16* __restrict__ Xt){
  __shared__ u16 tile[32][33];
  int b = blockIdx.z;
  const u16* src = X + (size_t)b * SEQ * DDIM;
  u16* dst = Xt + (size_t)b * SEQ * DDIM;
  int d0 = blockIdx.x * 32, t0 = blockIdx.y * 32;
  int tx = threadIdx.x;
  for(int i = threadIdx.y; i < 32; i += 8)
    tile[i][tx] = src[(size_t)(t0 + i) * DDIM + d0 + tx];
  __syncthreads();
  for(int i = threadIdx.y; i < 32; i += 8)
    dst[(size_t)(d0 + i) * SEQ + t0 + tx] = tile[tx][i];
}

// ============ pipelined bf16 GEMM: C = epilogue(A[M,K] . Bt[N,K]^T) ============
// BM=256 BN=128 BK=64, 8 waves (4Mx2N, 64x64 per wave), dbuf LDS, counted vmcnt,
// XOR-swizzled LDS (pre-swizzled global source + swizzled ds_read), setprio MFMA.
// N is always 1024 here (gn = 8 N-tiles, hardcoded). nwg = gm*8*gb, %8 == 0.
// MODE 0: C = [relu](acc + bias)    -> bf16
// MODE 1: C = exp(acc) -> bf16, rowsum[bz*SEQ+row] += sum_cols exp (atomic)
// MODE 2: C = acc * (1/rowsum[row]) -> bf16
template<int MODE, bool RELU>
__global__ __launch_bounds__(512, 2) void gemm_bt(
    const u16* __restrict__ A, const u16* __restrict__ Bt,
    const float* __restrict__ bias, float* __restrict__ rowsum,
    u16* __restrict__ Cv,
    int gm, int N, int K, long long bA, long long bB, long long bC)
{
  __shared__ u16 As[2][256][64];   // 64 KB
  __shared__ u16 Bs[2][128][64];   // 32 KB

  const int tid  = threadIdx.x;
  const int lane = tid & 63;
  const int wid  = tid >> 6;   // 0..7
  const int wr   = wid >> 1;   // 0..3 -> M
  const int wc   = wid & 1;    // 0..1 -> N

  // T1: bijective XCD swizzle (nwg % 8 == 0 for all call sites)
  int id = blockIdx.x;
  const int chunk = gridDim.x >> 3;
  id = (id & 7) * chunk + (id >> 3);
  const int tn = id & 7;
  const int tm = (id >> 3) % gm;
  const int bz = (id >> 3) / gm;

  const char* gAp = (const char*)(A  + (size_t)bz * bA + (size_t)tm * 256 * K);
  const char* gBp = (const char*)(Bt + (size_t)bz * bB + (size_t)tn * 128 * K);
  // staging: thread covers row (q*64 + tid>>3), 16B chunk (tid&7); global col
  // pre-swizzled so that linear LDS dest realizes the XOR layout (rule 21).
  const int colg = ((tid & 7) * 16) ^ (((tid >> 3) & 7) << 4);
  const char* gA0 = gAp + (size_t)(tid >> 3) * (K * 2) + colg;
  const char* gB0 = gBp + (size_t)(tid >> 3) * (K * 2) + colg;
  char* lA0 = (char*)&As[0][0][0] + tid * 16;
  char* lB0 = (char*)&Bs[0][0][0] + tid * 16;
  const int SLA = 256 * 64 * 2;   // bytes per A slot
  const int SLB = 128 * 64 * 2;

  auto stage = [&](int slot, int kt){
    const int g = kt * 2;
#pragma unroll
    for(int q = 0; q < 4; q++)
      load_lds16(gA0 + (size_t)q * 64 * K * 2 + g, lA0 + slot * SLA + q * 8192);
#pragma unroll
    for(int q = 0; q < 2; q++)
      load_lds16(gB0 + (size_t)q * 64 * K * 2 + g, lB0 + slot * SLB + q * 8192);
  };

  f32x4 acc[4][4];
#pragma unroll
  for(int i = 0; i < 4; i++)
#pragma unroll
    for(int j = 0; j < 4; j++){ acc[i][j][0]=0.f; acc[i][j][1]=0.f; acc[i][j][2]=0.f; acc[i][j][3]=0.f; }

  const int fr = lane & 15, kq = lane >> 4;
  int acol[2];
  acol[0] = (kq * 16) ^ ((fr & 7) << 4);   // ks=0, bytes within 128B row
  acol[1] = acol[0] ^ 64;                  // ks=1
  const char* aRd = (const char*)&As[0][0][0] + (wr * 64 + fr) * 128;
  const char* bRd = (const char*)&Bs[0][0][0] + (wc * 64 + fr) * 128;

  auto compute = [&](int slot){
    const char* ab = aRd + slot * SLA;
    const char* bb = bRd + slot * SLB;
    bf16x8 av[2][2], bv[4][2];
    // ---- phase 0: frags for mi 0..1 x all ni ----
#pragma unroll
    for(int mi = 0; mi < 2; mi++)
#pragma unroll
      for(int ks = 0; ks < 2; ks++)
        av[mi][ks] = *(const bf16x8*)(ab + mi * 2048 + acol[ks]);
#pragma unroll
    for(int ni = 0; ni < 4; ni++)
#pragma unroll
      for(int ks = 0; ks < 2; ks++)
        bv[ni][ks] = *(const bf16x8*)(bb + ni * 2048 + acol[ks]);
    SBAR();
    __builtin_amdgcn_s_setprio(1);
#pragma unroll
    for(int mi = 0; mi < 2; mi++)
#pragma unroll
      for(int ni = 0; ni < 4; ni++)
#pragma unroll
        for(int ks = 0; ks < 2; ks++)
          acc[mi][ni] = __builtin_amdgcn_mfma_f32_16x16x32_bf16(av[mi][ks], bv[ni][ks], acc[mi][ni], 0, 0, 0);
    __builtin_amdgcn_s_setprio(0);
    SBAR();
    // ---- phase 1: frags for mi 2..3 (B kept in regs) ----
#pragma unroll
    for(int mi = 0; mi < 2; mi++)
#pragma unroll
      for(int ks = 0; ks < 2; ks++)
        av[mi][ks] = *(const bf16x8*)(ab + (mi + 2) * 2048 + acol[ks]);
    SBAR();
    __builtin_amdgcn_s_setprio(1);
#pragma unroll
    for(int mi = 0; mi < 2; mi++)
#pragma unroll
      for(int ni = 0; ni < 4; ni++)
#pragma unroll
        for(int ks = 0; ks < 2; ks++)
          acc[mi + 2][ni] = __builtin_amdgcn_mfma_f32_16x16x32_bf16(av[mi][ks], bv[ni][ks], acc[mi + 2][ni], 0, 0, 0);
    __builtin_amdgcn_s_setprio(0);
    SBAR();   // also guards slot overwrite by the stage that follows
  };

  // ---- pipeline: depth-2 prefetch, counted vmcnt ----
  stage(0, 0);
  stage(1, 64);
  const int nkt = K >> 6;
  int slot = 0;
  for(int t = 0; t < nkt - 2; t++){
    asm volatile("s_waitcnt vmcnt(6)" ::: "memory");  // tile t landed; t+1 in flight
    SBAR();
    compute(slot);
    stage(slot, (t + 2) * 64);
    slot ^= 1;
  }
  asm volatile("s_waitcnt vmcnt(6)" ::: "memory");
  SBAR();
  compute(slot);
  slot ^= 1;
  asm volatile("s_waitcnt vmcnt(0)" ::: "memory");
  SBAR();
  compute(slot);

  // ---- epilogue: C/D layout col=lane&15, row=(lane>>4)*4+reg ----
  const int m0 = tm * 256 + wr * 64;
  const int n0 = tn * 128 + wc * 64;
  const int rq = lane >> 4;

  if(MODE == 0){
#pragma unroll
    for(int ni = 0; ni < 4; ni++){
      const int gcol = n0 + ni * 16 + fr;
      const float bv = bias[gcol];
#pragma unroll
      for(int mi = 0; mi < 4; mi++){
#pragma unroll
        for(int r = 0; r < 4; r++){
          const int grow = m0 + mi * 16 + rq * 4 + r;
          float v = acc[mi][ni][r] + bv;
          if(RELU) v = fmaxf(v, 0.f);
          Cv[(size_t)bz * bC + (size_t)grow * N + gcol] = f2b(v);
        }
      }
    }
  } else if(MODE == 1){
    float rs[4][4];
#pragma unroll
    for(int mi = 0; mi < 4; mi++)
#pragma unroll
      for(int r = 0; r < 4; r++) rs[mi][r] = 0.f;
#pragma unroll
    for(int ni = 0; ni < 4; ni++){
      const int gcol = n0 + ni * 16 + fr;
#pragma unroll
      for(int mi = 0; mi < 4; mi++){
#pragma unroll
        for(int r = 0; r < 4; r++){
          const int grow = m0 + mi * 16 + rq * 4 + r;
          float e = __expf(acc[mi][ni][r]);
          rs[mi][r] += e;
          Cv[(size_t)bz * bC + (size_t)grow * N + gcol] = f2b(e);
        }
      }
    }
#pragma unroll
    for(int off = 1; off < 16; off <<= 1)
#pragma unroll
      for(int mi = 0; mi < 4; mi++)
#pragma unroll
        for(int r = 0; r < 4; r++) rs[mi][r] += __shfl_xor(rs[mi][r], off);
    if(fr == 0){
#pragma unroll
      for(int mi = 0; mi < 4; mi++)
#pragma unroll
        for(int r = 0; r < 4; r++){
          const int grow = m0 + mi * 16 + rq * 4 + r;
          atomicAdd(&rowsum[bz * SEQ + grow], rs[mi][r]);
        }
    }
  } else {
    float inv[4][4];
#pragma unroll
    for(int mi = 0; mi < 4; mi++)
#pragma unroll
      for(int r = 0; r < 4; r++){
        const int grow = m0 + mi * 16 + rq * 4 + r;
        inv[mi][r] = __builtin_amdgcn_rcpf(rowsum[bz * SEQ + grow]);
      }
#pragma unroll
    for(int ni = 0; ni < 4; ni++){
      const int gcol = n0 + ni * 16 + fr;
#pragma unroll
      for(int mi = 0; mi < 4; mi++){
#pragma unroll
        for(int r = 0; r < 4; r++){
          const int grow = m0 + mi * 16 + rq * 4 + r;
          Cv[(size_t)bz * bC + (size_t)grow * N + gcol] = f2b(acc[mi][ni][r] * inv[mi][r]);
        }
      }
    }
  }
}

// ---------------- em = [p_cla | out2] @ W_hid + b_hid ----------------
__global__ __launch_bounds__(256) void em_kernel(const u16* __restrict__ out2,
                                                 const float* __restrict__ pcla,
                                                 const float* __restrict__ Whid,
                                                 const float* __restrict__ bhid,
                                                 float* __restrict__ em){
  const int row  = blockIdx.x * 4 + (threadIdx.x >> 6);
  const int lane = threadIdx.x & 63;
  float s[8] = {0.f,0.f,0.f,0.f,0.f,0.f,0.f,0.f};
  const u16* o2 = out2 + (size_t)row * 1024 + lane * 16;
#pragma unroll
  for(int h = 0; h < 2; h++){
    bf16x8 v = *(const bf16x8*)(o2 + h * 8);
#pragma unroll
    for(int e = 0; e < 8; e++){
      const float od = b2f((u16)v[e]);
      const int d = lane * 16 + h * 8 + e;
      const float* wr = Whid + (size_t)(NP + d) * 8;
#pragma unroll
      for(int j = 0; j < 8; j++) s[j] += od * wr[j];
    }
  }
#pragma unroll
  for(int q = 0; q < 2; q++){
    const int p = lane * 2 + q;
    const float pv = pcla[(size_t)row * NP + p];
    const float* wr = Whid + (size_t)p * 8;
#pragma unroll
    for(int j = 0; j < 8; j++) s[j] += pv * wr[j];
  }
#pragma unroll
  for(int off = 1; off < 64; off <<= 1)
#pragma unroll
    for(int j = 0; j < 8; j++) s[j] += __shfl_xor(s[j], off);
  if(lane == 0){
#pragma unroll
    for(int j = 0; j < 8; j++) em[(size_t)row * 8 + j] = s[j] + bhid[j];
  }
}

// ---------------- CRF NLL per batch (prob-domain chunked scan + tree) ----------------
__global__ __launch_bounds__(256) void crf_kernel(const float* __restrict__ em,
                                                  const int* __restrict__ tags,
                                                  const float* __restrict__ cstart,
                                                  const float* __restrict__ cend,
                                                  const float* __restrict__ ctrans,
                                                  float* __restrict__ partial){
  const int b = blockIdx.x;
  const int tid = threadIdx.x;
  const float* emb = em + (size_t)b * SEQ * 8;
  const int* tg = tags + b * SEQ;

  __shared__ float Mbuf[128][64];
  __shared__ float Mbuf2[64][64];
  __shared__ float ls1[128], ls2[64];
  __shared__ float etr_s[64];
  __shared__ float mxs[64];
  __shared__ float red[256];

  if(tid < 64) etr_s[tid] = expf(ctrans[tid]);

  float loc = 0.f;
  for(int t = tid; t < SEQ; t += 256){
    const int tgt = tg[t];
    loc += emb[t * 8 + tgt];
    if(t < SEQ - 1) loc += ctrans[tgt * 8 + tg[t + 1]];
  }
  if(tid == 0) loc += cstart[tg[0]] + cend[tg[SEQ - 1]];
  red[tid] = loc;
  __syncthreads();
  for(int s = 128; s > 0; s >>= 1){
    if(tid < s) red[tid] += red[tid + s];
    __syncthreads();
  }

  if(tid < 128){
    const int c = tid;
    const int t0 = (c == 0) ? 1 : c * 8;
    const int t1 = c * 8 + 8;
    float etr[64];
#pragma unroll
    for(int i = 0; i < 64; i++) etr[i] = etr_s[i];
    float acc[64];
    float ej[8];
#pragma unroll
    for(int j = 0; j < 8; j++) ej[j] = expf(emb[t0 * 8 + j]);
#pragma unroll
    for(int i = 0; i < 8; i++)
#pragma unroll
      for(int j = 0; j < 8; j++) acc[i * 8 + j] = etr[i * 8 + j] * ej[j];
    for(int t = t0 + 1; t < t1; t++){
#pragma unroll
      for(int j = 0; j < 8; j++) ej[j] = expf(emb[t * 8 + j]);
#pragma unroll
      for(int i = 0; i < 8; i++){
        float tmp[8];
#pragma unroll
        for(int j = 0; j < 8; j++){
          float sv = 0.f;
#pragma unroll
          for(int k = 0; k < 8; k++) sv += acc[i * 8 + k] * etr[k * 8 + j];
          tmp[j] = sv * ej[j];
        }
#pragma unroll
        for(int j = 0; j < 8; j++) acc[i * 8 + j] = tmp[j];
      }
    }
    float mx = acc[0];
#pragma unroll
    for(int i = 1; i < 64; i++) mx = fmaxf(mx, acc[i]);
    const float im = 1.f / mx;
#pragma unroll
    for(int i = 0; i < 64; i++) Mbuf[c][i] = acc[i] * im;
    ls1[c] = logf(mx);
  }
  __syncthreads();

  float* src = &Mbuf[0][0];  float* dst = &Mbuf2[0][0];
  float* lsrc = ls1;         float* ldst = ls2;
  for(int n = 64; n >= 1; n >>= 1){
    for(int idx = tid; idx < n * 64; idx += 256){
      const int p = idx >> 6, e = idx & 63, i = e >> 3, j = e & 7;
      const float* Am = src + (size_t)(2 * p) * 64;
      const float* Bm = src + (size_t)(2 * p + 1) * 64;
      float sv = 0.f;
#pragma unroll
      for(int k = 0; k < 8; k++) sv += Am[i * 8 + k] * Bm[k * 8 + j];
      dst[(size_t)p * 64 + e] = sv;
    }
    __syncthreads();
    if(tid < n){
      const float* Cm = dst + (size_t)tid * 64;
      float mx = Cm[0];
#pragma unroll
      for(int i = 1; i < 64; i++) mx = fmaxf(mx, Cm[i]);
      mxs[tid] = 1.f / mx;
      ldst[tid] = lsrc[2 * tid] + lsrc[2 * tid + 1] + logf(mx);
    }
    __syncthreads();
    for(int idx = tid; idx < n * 64; idx += 256)
      dst[idx] *= mxs[idx >> 6];
    __syncthreads();
    float* tf = src; src = dst; dst = tf;
    float* tl = lsrc; lsrc = ldst; ldst = tl;
  }

  if(tid == 0){
    float a0[8];
#pragma unroll
    for(int i = 0; i < 8; i++) a0[i] = expf(cstart[i] + emb[i]);
    float z = 0.f;
#pragma unroll
    for(int j = 0; j < 8; j++){
      float t = 0.f;
#pragma unroll
      for(int i = 0; i < 8; i++) t += a0[i] * src[i * 8 + j];
      z += t * expf(cend[j]);
    }
    const float logZ = logf(z) + lsrc[0];
    partial[b] = logZ - red[0];
  }
}

__global__ void final_sum(const float* __restrict__ partial, float* __restrict__ out){
  if(threadIdx.x == 0){
    float s = 0.f;
    for(int b = 0; b < NB; b++) s += partial[b];
    out[0] = s;
  }
}

// ---------------- launch ----------------
extern "C" void kernel_launch(void* const* d_in, const int* in_sizes, int n_in,
                              void* d_out, int out_size, void* d_ws, size_t ws_size,
                              hipStream_t stream){
  (void)in_sizes; (void)n_in; (void)out_size; (void)ws_size;
  const float* x      = (const float*)d_in[0];
  const float* p_cla  = (const float*)d_in[1];
  const float* W_emo  = (const float*)d_in[2];
  const float* b_emo  = (const float*)d_in[3];
  const float* W_att  = (const float*)d_in[4];
  const float* b_att  = (const float*)d_in[5];
  const float* W_hid  = (const float*)d_in[6];
  const float* b_hid  = (const float*)d_in[7];
  const float* cstart = (const float*)d_in[8];
  const float* cend   = (const float*)d_in[9];
  const float* ctrans = (const float*)d_in[10];
  const int*   tags   = (const int*)d_in[11];

  char* ws = (char*)d_ws;
  const size_t MB = 1u << 20;
  u16*   xb     = (u16*)(ws + 0 * MB);        // 16MB
  u16*   wemoT  = (u16*)(ws + 16 * MB);       // 2MB
  u16*   wattT  = (u16*)(ws + 18 * MB);       // 2MB
  u16*   out_b  = (u16*)(ws + 20 * MB);       // 16MB
  u16*   outT   = (u16*)(ws + 36 * MB);       // 16MB
  u16*   oatt   = (u16*)(ws + 52 * MB);       // 16MB
  u16*   scores = (u16*)(ws + 68 * MB);       // 16MB (unnormalized exp, bf16)
  u16*   out2   = (u16*)(ws + 84 * MB);       // 16MB
  float* em     = (float*)(ws + 100 * MB);    // 256KB
  float* part   = (float*)(ws + 100 * MB + 262144);
  float* rowsum = (float*)(ws + 100 * MB + 524288);  // 32KB

  const long long bs = (long long)SEQ * DDIM;

  cvt_f32_bf16<<<8192, 256, 0, stream>>>(x, xb, NB * SEQ * DDIM);
  transpose_w2<<<dim3(32, 32, 2), dim3(32, 8), 0, stream>>>(W_emo, W_att, wemoT, wattT, rowsum);

  // out = relu(x @ W_emo + b_emo) ; grid = gm*gn*gb = 32*8*1 = 256
  gemm_bt<0, true><<<256, 512, 0, stream>>>(
      xb, wemoT, b_emo, nullptr, out_b, 32, DDIM, DDIM, 0, 0, 0);
  // V^T for PV
  transpose_b16<<<dim3(32, 32, NB), dim3(32, 8), 0, stream>>>(out_b, outT);
  // out_att = out @ W_att + b_att
  gemm_bt<0, false><<<256, 512, 0, stream>>>(
      out_b, wattT, b_att, nullptr, oatt, 32, DDIM, DDIM, 0, 0, 0);
  // scores[b] = exp(out_att[b] @ out[b]^T) (bf16) + rowsum atomics ; 4*8*8 = 256
  gemm_bt<1, false><<<256, 512, 0, stream>>>(
      oatt, out_b, nullptr, rowsum, scores, 4, SEQ, DDIM, bs, bs, bs);
  // out2[b] = (scores[b] @ out[b]) / rowsum
  gemm_bt<2, false><<<256, 512, 0, stream>>>(
      scores, outT, nullptr, rowsum, out2, 4, SEQ, DDIM, bs, bs, bs);
  // em = [p_cla | out2] @ W_hid + b_hid
  em_kernel<<<2048, 256, 0, stream>>>(out2, p_cla, W_hid, b_hid, em);
  // CRF NLL
  crf_kernel<<<NB, 256, 0, stream>>>(em, tags, cstart, cend, ctrans, part);
  final_sum<<<1, 64, 0, stream>>>(part, (float*)d_out);
}

// Round 4
// 181.500 us; speedup vs baseline: 1.1836x; 1.0638x over previous
//
#include <hip/hip_runtime.h>
#include <stdint.h>

typedef unsigned short u16;
typedef __attribute__((ext_vector_type(8))) short bf16x8;
typedef __attribute__((ext_vector_type(4))) float f32x4;

#define NB 8
#define SEQ 1024
#define DDIM 1024
#define NP 128
#define NT 8
#define GK 1024           // K for all GEMMs
#define NKT 16            // GK/64

__device__ __forceinline__ u16 f2b(float f){
  union { float f; uint32_t u; } v; v.f = f;
  return (u16)((v.u + 0x7FFFu + ((v.u >> 16) & 1u)) >> 16);
}
__device__ __forceinline__ float b2f(u16 h){
  union { uint32_t u; float f; } v; v.u = ((uint32_t)h) << 16; return v.f;
}

__device__ __forceinline__ void load_lds16(const void* g, void* l){
  __builtin_amdgcn_global_load_lds((const __attribute__((address_space(1))) void*)g,
                                   (__attribute__((address_space(3))) void*)l,
                                   16, 0, 0);
}

#define MEMFENCE asm volatile("" ::: "memory")
#define SBAR() do { MEMFENCE; __builtin_amdgcn_s_barrier(); MEMFENCE; } while(0)

// ------- merged prep: f32->bf16 convert of x  +  2 weight transposes + rowsum zero -------
__global__ __launch_bounds__(256) void prep_kernel(const float* __restrict__ x,
                                                   u16* __restrict__ xb,
                                                   const float* __restrict__ W0,
                                                   const float* __restrict__ W1,
                                                   u16* __restrict__ T0,
                                                   u16* __restrict__ T1,
                                                   float* __restrict__ rowsum){
  __shared__ float tile[32][33];
  const int bid = blockIdx.x;
  const int tid = threadIdx.x;
  if(bid < 8192){
    // convert: 8M elements, 4/thread
    int idx = (bid * 256 + tid) * 4;
    float4 v = *(const float4*)(x + idx);
    ushort4 o;
    o.x = f2b(v.x); o.y = f2b(v.y); o.z = f2b(v.z); o.w = f2b(v.w);
    *(ushort4*)(xb + idx) = o;
  } else {
    const int b2 = bid - 8192;                 // 0..2047
    const int z  = b2 >> 10;                   // 0/1 -> which weight
    const int bx = b2 & 31, by = (b2 >> 5) & 31;
    const int tx = tid & 31, ty = tid >> 5;    // 32 x 8
    const float* W = z ? W1 : W0;
    u16* Wt = z ? T1 : T0;
    const int c0 = bx * 32, r0 = by * 32;
    for(int i = ty; i < 32; i += 8)
      tile[i][tx] = W[(size_t)(r0 + i) * DDIM + c0 + tx];
    __syncthreads();
    for(int i = ty; i < 32; i += 8)
      Wt[(size_t)(c0 + i) * DDIM + r0 + tx] = f2b(tile[tx][i]);
    if(z == 0 && by == 0)
      rowsum[bx * 256 + tid] = 0.f;
  }
}

// ---------------- bf16 [b][t][d] -> [b][d][t] transpose ----------------
__global__ __launch_bounds__(256) void transpose_b16(const u16* __restrict__ X,
                                                     u16* __restrict__ Xt){
  __shared__ u16 tile[32][33];
  int b = blockIdx.z;
  const u16* src = X + (size_t)b * SEQ * DDIM;
  u16* dst = Xt + (size_t)b * SEQ * DDIM;
  int d0 = blockIdx.x * 32, t0 = blockIdx.y * 32;
  int tx = threadIdx.x;
  for(int i = threadIdx.y; i < 32; i += 8)
    tile[i][tx] = src[(size_t)(t0 + i) * DDIM + d0 + tx];
  __syncthreads();
  for(int i = threadIdx.y; i < 32; i += 8)
    dst[(size_t)(d0 + i) * SEQ + t0 + tx] = tile[tx][i];
}

// ============ pipelined bf16 GEMM: C = epilogue(A[M,1024] . Bt[N,1024]^T) ============
// BM=256 BN=128 BK=64, 8 waves (4Mx2N), TRIPLE-buffered LDS, counted vmcnt(12),
// 2 barriers per K-tile, XOR-swizzled LDS via pre-swizzled global source,
// setprio around MFMA clusters, bijective XCD swizzle.
// MODE 0: C = [relu](acc + bias)    -> bf16
// MODE 1: C = exp(acc) -> bf16, rowsum[bz*SEQ+row] += sum_cols exp (atomic)
// MODE 2: C = acc * (1/rowsum[row]) -> bf16
template<int MODE, bool RELU>
__global__ __launch_bounds__(512, 2) void gemm_bt(
    const u16* __restrict__ A, const u16* __restrict__ Bt,
    const float* __restrict__ bias, float* __restrict__ rowsum,
    u16* __restrict__ Cv,
    int gm, int N, long long bA, long long bB, long long bC)
{
  __shared__ u16 As[3][256][64];   // 96 KB
  __shared__ u16 Bs[3][128][64];   // 48 KB

  const int tid  = threadIdx.x;
  const int lane = tid & 63;
  const int wid  = tid >> 6;   // 0..7
  const int wr   = wid >> 1;   // 0..3 -> M
  const int wc   = wid & 1;    // 0..1 -> N

  // T1: bijective XCD swizzle (gridDim.x % 8 == 0 at all call sites)
  int id = blockIdx.x;
  const int chunk = gridDim.x >> 3;
  id = (id & 7) * chunk + (id >> 3);
  const int tn = id & 7;
  const int tm = (id >> 3) % gm;
  const int bz = (id >> 3) / gm;

  const char* gAp = (const char*)(A  + (size_t)bz * bA + (size_t)tm * 256 * GK);
  const char* gBp = (const char*)(Bt + (size_t)bz * bB + (size_t)tn * 128 * GK);
  // staging: thread covers row (q*64 + tid>>3), 16B chunk (tid&7); global col
  // pre-swizzled so the linear LDS dest realizes the XOR layout (rule 21).
  const int colg = ((tid & 7) * 16) ^ (((tid >> 3) & 7) << 4);
  const char* gA0 = gAp + (size_t)(tid >> 3) * 2048 + colg;
  const char* gB0 = gBp + (size_t)(tid >> 3) * 2048 + colg;
  char* lA0 = (char*)&As[0][0][0] + tid * 16;
  char* lB0 = (char*)&Bs[0][0][0] + tid * 16;
  const int SLA = 256 * 64 * 2;   // bytes per A slot
  const int SLB = 128 * 64 * 2;

  auto stage = [&](int slot, int kt){
    const int g = kt * 2;
#pragma unroll
    for(int q = 0; q < 4; q++)
      load_lds16(gA0 + (size_t)q * 64 * 2048 + g, lA0 + slot * SLA + q * 8192);
#pragma unroll
    for(int q = 0; q < 2; q++)
      load_lds16(gB0 + (size_t)q * 64 * 2048 + g, lB0 + slot * SLB + q * 8192);
  };

  f32x4 acc[4][4];
#pragma unroll
  for(int i = 0; i < 4; i++)
#pragma unroll
    for(int j = 0; j < 4; j++){ acc[i][j][0]=0.f; acc[i][j][1]=0.f; acc[i][j][2]=0.f; acc[i][j][3]=0.f; }

  const int fr = lane & 15, kq = lane >> 4;
  int acol[2];
  acol[0] = (kq * 16) ^ ((fr & 7) << 4);   // ks=0, bytes within 128B row
  acol[1] = acol[0] ^ 64;                  // ks=1
  const char* aRd = (const char*)&As[0][0][0] + (wr * 64 + fr) * 128;
  const char* bRd = (const char*)&Bs[0][0][0] + (wc * 64 + fr) * 128;

  auto compute = [&](int slot){
    const char* ab = aRd + slot * SLA;
    const char* bb = bRd + slot * SLB;
    bf16x8 av[2][2], bv[4][2];
#pragma unroll
    for(int mi = 0; mi < 2; mi++)
#pragma unroll
      for(int ks = 0; ks < 2; ks++)
        av[mi][ks] = *(const bf16x8*)(ab + mi * 2048 + acol[ks]);
#pragma unroll
    for(int ni = 0; ni < 4; ni++)
#pragma unroll
      for(int ks = 0; ks < 2; ks++)
        bv[ni][ks] = *(const bf16x8*)(bb + ni * 2048 + acol[ks]);
    __builtin_amdgcn_s_setprio(1);
#pragma unroll
    for(int mi = 0; mi < 2; mi++)
#pragma unroll
      for(int ni = 0; ni < 4; ni++)
#pragma unroll
        for(int ks = 0; ks < 2; ks++)
          acc[mi][ni] = __builtin_amdgcn_mfma_f32_16x16x32_bf16(av[mi][ks], bv[ni][ks], acc[mi][ni], 0, 0, 0);
    __builtin_amdgcn_s_setprio(0);
    bf16x8 aw[2][2];
#pragma unroll
    for(int mi = 0; mi < 2; mi++)
#pragma unroll
      for(int ks = 0; ks < 2; ks++)
        aw[mi][ks] = *(const bf16x8*)(ab + (mi + 2) * 2048 + acol[ks]);
    __builtin_amdgcn_s_setprio(1);
#pragma unroll
    for(int mi = 0; mi < 2; mi++)
#pragma unroll
      for(int ni = 0; ni < 4; ni++)
#pragma unroll
        for(int ks = 0; ks < 2; ks++)
          acc[mi + 2][ni] = __builtin_amdgcn_mfma_f32_16x16x32_bf16(aw[mi][ks], bv[ni][ks], acc[mi + 2][ni], 0, 0, 0);
    __builtin_amdgcn_s_setprio(0);
  };

  // ---- pipeline: depth-3 prefetch, counted vmcnt(12), 2 barriers/tile ----
  stage(0, 0);
  stage(1, 64);
  stage(2, 128);
  int slot = 0;
  for(int t = 0; t < NKT - 3; t++){
    asm volatile("s_waitcnt vmcnt(12)" ::: "memory");  // tile t landed (t+1,t+2 in flight)
    SBAR();
    compute(slot);
    SBAR();                                            // all waves done reading slot
    stage(slot, (t + 3) * 64);
    slot = (slot == 2) ? 0 : slot + 1;
  }
  asm volatile("s_waitcnt vmcnt(12)" ::: "memory");    // tile NKT-3
  SBAR();
  compute(slot);
  slot = (slot == 2) ? 0 : slot + 1;
  asm volatile("s_waitcnt vmcnt(6)" ::: "memory");     // tile NKT-2
  SBAR();
  compute(slot);
  slot = (slot == 2) ? 0 : slot + 1;
  asm volatile("s_waitcnt vmcnt(0)" ::: "memory");     // tile NKT-1
  SBAR();
  compute(slot);

  // ---- epilogue: C/D layout col=lane&15, row=(lane>>4)*4+reg ----
  const int m0 = tm * 256 + wr * 64;
  const int n0 = tn * 128 + wc * 64;
  const int rq = lane >> 4;

  if(MODE == 0){
#pragma unroll
    for(int ni = 0; ni < 4; ni++){
      const int gcol = n0 + ni * 16 + fr;
      const float bv = bias[gcol];
#pragma unroll
      for(int mi = 0; mi < 4; mi++){
#pragma unroll
        for(int r = 0; r < 4; r++){
          const int grow = m0 + mi * 16 + rq * 4 + r;
          float v = acc[mi][ni][r] + bv;
          if(RELU) v = fmaxf(v, 0.f);
          Cv[(size_t)bz * bC + (size_t)grow * N + gcol] = f2b(v);
        }
      }
    }
  } else if(MODE == 1){
    float rs[4][4];
#pragma unroll
    for(int mi = 0; mi < 4; mi++)
#pragma unroll
      for(int r = 0; r < 4; r++) rs[mi][r] = 0.f;
#pragma unroll
    for(int ni = 0; ni < 4; ni++){
      const int gcol = n0 + ni * 16 + fr;
#pragma unroll
      for(int mi = 0; mi < 4; mi++){
#pragma unroll
        for(int r = 0; r < 4; r++){
          const int grow = m0 + mi * 16 + rq * 4 + r;
          float e = __expf(acc[mi][ni][r]);
          rs[mi][r] += e;
          Cv[(size_t)bz * bC + (size_t)grow * N + gcol] = f2b(e);
        }
      }
    }
#pragma unroll
    for(int off = 1; off < 16; off <<= 1)
#pragma unroll
      for(int mi = 0; mi < 4; mi++)
#pragma unroll
        for(int r = 0; r < 4; r++) rs[mi][r] += __shfl_xor(rs[mi][r], off);
    if(fr == 0){
#pragma unroll
      for(int mi = 0; mi < 4; mi++)
#pragma unroll
        for(int r = 0; r < 4; r++){
          const int grow = m0 + mi * 16 + rq * 4 + r;
          atomicAdd(&rowsum[bz * SEQ + grow], rs[mi][r]);
        }
    }
  } else {
    float inv[4][4];
#pragma unroll
    for(int mi = 0; mi < 4; mi++)
#pragma unroll
      for(int r = 0; r < 4; r++){
        const int grow = m0 + mi * 16 + rq * 4 + r;
        inv[mi][r] = __builtin_amdgcn_rcpf(rowsum[bz * SEQ + grow]);
      }
#pragma unroll
    for(int ni = 0; ni < 4; ni++){
      const int gcol = n0 + ni * 16 + fr;
#pragma unroll
      for(int mi = 0; mi < 4; mi++){
#pragma unroll
        for(int r = 0; r < 4; r++){
          const int grow = m0 + mi * 16 + rq * 4 + r;
          Cv[(size_t)bz * bC + (size_t)grow * N + gcol] = f2b(acc[mi][ni][r] * inv[mi][r]);
        }
      }
    }
  }
}

// ---------------- em = [p_cla | out2] @ W_hid + b_hid ----------------
__global__ __launch_bounds__(256) void em_kernel(const u16* __restrict__ out2,
                                                 const float* __restrict__ pcla,
                                                 const float* __restrict__ Whid,
                                                 const float* __restrict__ bhid,
                                                 float* __restrict__ em){
  const int row  = blockIdx.x * 4 + (threadIdx.x >> 6);
  const int lane = threadIdx.x & 63;
  float s[8] = {0.f,0.f,0.f,0.f,0.f,0.f,0.f,0.f};
  const u16* o2 = out2 + (size_t)row * 1024 + lane * 16;
#pragma unroll
  for(int h = 0; h < 2; h++){
    bf16x8 v = *(const bf16x8*)(o2 + h * 8);
#pragma unroll
    for(int e = 0; e < 8; e++){
      const float od = b2f((u16)v[e]);
      const int d = lane * 16 + h * 8 + e;
      const float* wr = Whid + (size_t)(NP + d) * 8;
#pragma unroll
      for(int j = 0; j < 8; j++) s[j] += od * wr[j];
    }
  }
#pragma unroll
  for(int q = 0; q < 2; q++){
    const int p = lane * 2 + q;
    const float pv = pcla[(size_t)row * NP + p];
    const float* wr = Whid + (size_t)p * 8;
#pragma unroll
    for(int j = 0; j < 8; j++) s[j] += pv * wr[j];
  }
#pragma unroll
  for(int off = 1; off < 64; off <<= 1)
#pragma unroll
    for(int j = 0; j < 8; j++) s[j] += __shfl_xor(s[j], off);
  if(lane == 0){
#pragma unroll
    for(int j = 0; j < 8; j++) em[(size_t)row * 8 + j] = s[j] + bhid[j];
  }
}

// ---------------- CRF NLL per batch (prob-domain chunked scan + tree) ----------------
__global__ __launch_bounds__(256) void crf_kernel(const float* __restrict__ em,
                                                  const int* __restrict__ tags,
                                                  const float* __restrict__ cstart,
                                                  const float* __restrict__ cend,
                                                  const float* __restrict__ ctrans,
                                                  float* __restrict__ partial){
  const int b = blockIdx.x;
  const int tid = threadIdx.x;
  const float* emb = em + (size_t)b * SEQ * 8;
  const int* tg = tags + b * SEQ;

  __shared__ float Mbuf[128][64];
  __shared__ float Mbuf2[64][64];
  __shared__ float ls1[128], ls2[64];
  __shared__ float etr_s[64];
  __shared__ float mxs[64];
  __shared__ float red[256];

  if(tid < 64) etr_s[tid] = expf(ctrans[tid]);

  float loc = 0.f;
  for(int t = tid; t < SEQ; t += 256){
    const int tgt = tg[t];
    loc += emb[t * 8 + tgt];
    if(t < SEQ - 1) loc += ctrans[tgt * 8 + tg[t + 1]];
  }
  if(tid == 0) loc += cstart[tg[0]] + cend[tg[SEQ - 1]];
  red[tid] = loc;
  __syncthreads();
  for(int s = 128; s > 0; s >>= 1){
    if(tid < s) red[tid] += red[tid + s];
    __syncthreads();
  }

  if(tid < 128){
    const int c = tid;
    const int t0 = (c == 0) ? 1 : c * 8;
    const int t1 = c * 8 + 8;
    float etr[64];
#pragma unroll
    for(int i = 0; i < 64; i++) etr[i] = etr_s[i];
    float acc[64];
    float ej[8];
#pragma unroll
    for(int j = 0; j < 8; j++) ej[j] = expf(emb[t0 * 8 + j]);
#pragma unroll
    for(int i = 0; i < 8; i++)
#pragma unroll
      for(int j = 0; j < 8; j++) acc[i * 8 + j] = etr[i * 8 + j] * ej[j];
    for(int t = t0 + 1; t < t1; t++){
#pragma unroll
      for(int j = 0; j < 8; j++) ej[j] = expf(emb[t * 8 + j]);
#pragma unroll
      for(int i = 0; i < 8; i++){
        float tmp[8];
#pragma unroll
        for(int j = 0; j < 8; j++){
          float sv = 0.f;
#pragma unroll
          for(int k = 0; k < 8; k++) sv += acc[i * 8 + k] * etr[k * 8 + j];
          tmp[j] = sv * ej[j];
        }
#pragma unroll
        for(int j = 0; j < 8; j++) acc[i * 8 + j] = tmp[j];
      }
    }
    float mx = acc[0];
#pragma unroll
    for(int i = 1; i < 64; i++) mx = fmaxf(mx, acc[i]);
    const float im = 1.f / mx;
#pragma unroll
    for(int i = 0; i < 64; i++) Mbuf[c][i] = acc[i] * im;
    ls1[c] = logf(mx);
  }
  __syncthreads();

  float* src = &Mbuf[0][0];  float* dst = &Mbuf2[0][0];
  float* lsrc = ls1;         float* ldst = ls2;
  for(int n = 64; n >= 1; n >>= 1){
    for(int idx = tid; idx < n * 64; idx += 256){
      const int p = idx >> 6, e = idx & 63, i = e >> 3, j = e & 7;
      const float* Am = src + (size_t)(2 * p) * 64;
      const float* Bm = src + (size_t)(2 * p + 1) * 64;
      float sv = 0.f;
#pragma unroll
      for(int k = 0; k < 8; k++) sv += Am[i * 8 + k] * Bm[k * 8 + j];
      dst[(size_t)p * 64 + e] = sv;
    }
    __syncthreads();
    if(tid < n){
      const float* Cm = dst + (size_t)tid * 64;
      float mx = Cm[0];
#pragma unroll
      for(int i = 1; i < 64; i++) mx = fmaxf(mx, Cm[i]);
      mxs[tid] = 1.f / mx;
      ldst[tid] = lsrc[2 * tid] + lsrc[2 * tid + 1] + logf(mx);
    }
    __syncthreads();
    for(int idx = tid; idx < n * 64; idx += 256)
      dst[idx] *= mxs[idx >> 6];
    __syncthreads();
    float* tf = src; src = dst; dst = tf;
    float* tl = lsrc; lsrc = ldst; ldst = tl;
  }

  if(tid == 0){
    float a0[8];
#pragma unroll
    for(int i = 0; i < 8; i++) a0[i] = expf(cstart[i] + emb[i]);
    float z = 0.f;
#pragma unroll
    for(int j = 0; j < 8; j++){
      float t = 0.f;
#pragma unroll
      for(int i = 0; i < 8; i++) t += a0[i] * src[i * 8 + j];
      z += t * expf(cend[j]);
    }
    const float logZ = logf(z) + lsrc[0];
    partial[b] = logZ - red[0];
  }
}

__global__ void final_sum(const float* __restrict__ partial, float* __restrict__ out){
  if(threadIdx.x == 0){
    float s = 0.f;
    for(int b = 0; b < NB; b++) s += partial[b];
    out[0] = s;
  }
}

// ---------------- launch ----------------
extern "C" void kernel_launch(void* const* d_in, const int* in_sizes, int n_in,
                              void* d_out, int out_size, void* d_ws, size_t ws_size,
                              hipStream_t stream){
  (void)in_sizes; (void)n_in; (void)out_size; (void)ws_size;
  const float* x      = (const float*)d_in[0];
  const float* p_cla  = (const float*)d_in[1];
  const float* W_emo  = (const float*)d_in[2];
  const float* b_emo  = (const float*)d_in[3];
  const float* W_att  = (const float*)d_in[4];
  const float* b_att  = (const float*)d_in[5];
  const float* W_hid  = (const float*)d_in[6];
  const float* b_hid  = (const float*)d_in[7];
  const float* cstart = (const float*)d_in[8];
  const float* cend   = (const float*)d_in[9];
  const float* ctrans = (const float*)d_in[10];
  const int*   tags   = (const int*)d_in[11];

  char* ws = (char*)d_ws;
  const size_t MB = 1u << 20;
  u16*   xb     = (u16*)(ws + 0 * MB);        // 16MB
  u16*   wemoT  = (u16*)(ws + 16 * MB);       // 2MB
  u16*   wattT  = (u16*)(ws + 18 * MB);       // 2MB
  u16*   out_b  = (u16*)(ws + 20 * MB);       // 16MB
  u16*   outT   = (u16*)(ws + 36 * MB);       // 16MB
  u16*   oatt   = (u16*)(ws + 52 * MB);       // 16MB
  u16*   scores = (u16*)(ws + 68 * MB);       // 16MB (unnormalized exp, bf16)
  u16*   out2   = (u16*)(ws + 84 * MB);       // 16MB
  float* em     = (float*)(ws + 100 * MB);    // 256KB
  float* part   = (float*)(ws + 100 * MB + 262144);
  float* rowsum = (float*)(ws + 100 * MB + 524288);  // 32KB

  const long long bs = (long long)SEQ * DDIM;

  // convert x + transpose both weights + zero rowsum, one launch
  prep_kernel<<<8192 + 2048, 256, 0, stream>>>(x, xb, W_emo, W_att, wemoT, wattT, rowsum);

  // out = relu(x @ W_emo + b_emo) ; grid = gm*gn*gb = 32*8*1 = 256
  gemm_bt<0, true><<<256, 512, 0, stream>>>(
      xb, wemoT, b_emo, nullptr, out_b, 32, DDIM, 0, 0, 0);
  // V^T for PV
  transpose_b16<<<dim3(32, 32, NB), dim3(32, 8), 0, stream>>>(out_b, outT);
  // out_att = out @ W_att + b_att
  gemm_bt<0, false><<<256, 512, 0, stream>>>(
      out_b, wattT, b_att, nullptr, oatt, 32, DDIM, 0, 0, 0);
  // scores[b] = exp(out_att[b] @ out[b]^T) (bf16) + rowsum atomics ; 4*8*8 = 256
  gemm_bt<1, false><<<256, 512, 0, stream>>>(
      oatt, out_b, nullptr, rowsum, scores, 4, SEQ, bs, bs, bs);
  // out2[b] = (scores[b] @ out[b]) / rowsum
  gemm_bt<2, false><<<256, 512, 0, stream>>>(
      scores, outT, nullptr, rowsum, out2, 4, SEQ, bs, bs, bs);
  // em = [p_cla | out2] @ W_hid + b_hid
  em_kernel<<<2048, 256, 0, stream>>>(out2, p_cla, W_hid, b_hid, em);
  // CRF NLL
  crf_kernel<<<NB, 256, 0, stream>>>(em, tags, cstart, cend, ctrans, part);
  final_sum<<<1, 64, 0, stream>>>(part, (float*)d_out);
}

// Round 5
// 174.634 us; speedup vs baseline: 1.2301x; 1.0393x over previous
//
#include <hip/hip_runtime.h>
#include <stdint.h>

typedef unsigned short u16;
typedef __attribute__((ext_vector_type(8))) short bf16x8;
typedef __attribute__((ext_vector_type(4))) float f32x4;

#define NB 8
#define SEQ 1024
#define DDIM 1024
#define NP 128
#define NT 8
#define GK 1024           // K for all GEMMs
#define NKT 16            // GK/64

__device__ __forceinline__ u16 f2b(float f){
  union { float f; uint32_t u; } v; v.f = f;
  return (u16)((v.u + 0x7FFFu + ((v.u >> 16) & 1u)) >> 16);
}
__device__ __forceinline__ float b2f(u16 h){
  union { uint32_t u; float f; } v; v.u = ((uint32_t)h) << 16; return v.f;
}

__device__ __forceinline__ void load_lds16(const void* g, void* l){
  __builtin_amdgcn_global_load_lds((const __attribute__((address_space(1))) void*)g,
                                   (__attribute__((address_space(3))) void*)l,
                                   16, 0, 0);
}

#define MEMFENCE asm volatile("" ::: "memory")
#define SBAR() do { MEMFENCE; __builtin_amdgcn_s_barrier(); MEMFENCE; } while(0)

// ------- merged prep: f32->bf16 convert of x  +  2 weight transposes + rowsum zero -------
__global__ __launch_bounds__(256) void prep_kernel(const float* __restrict__ x,
                                                   u16* __restrict__ xb,
                                                   const float* __restrict__ W0,
                                                   const float* __restrict__ W1,
                                                   u16* __restrict__ T0,
                                                   u16* __restrict__ T1,
                                                   float* __restrict__ rowsum){
  __shared__ float tile[32][33];
  const int bid = blockIdx.x;
  const int tid = threadIdx.x;
  if(bid < 8192){
    int idx = (bid * 256 + tid) * 4;
    float4 v = *(const float4*)(x + idx);
    ushort4 o;
    o.x = f2b(v.x); o.y = f2b(v.y); o.z = f2b(v.z); o.w = f2b(v.w);
    *(ushort4*)(xb + idx) = o;
  } else {
    const int b2 = bid - 8192;                 // 0..2047
    const int z  = b2 >> 10;                   // 0/1 -> which weight
    const int bx = b2 & 31, by = (b2 >> 5) & 31;
    const int tx = tid & 31, ty = tid >> 5;    // 32 x 8
    const float* W = z ? W1 : W0;
    u16* Wt = z ? T1 : T0;
    const int c0 = bx * 32, r0 = by * 32;
    for(int i = ty; i < 32; i += 8)
      tile[i][tx] = W[(size_t)(r0 + i) * DDIM + c0 + tx];
    __syncthreads();
    for(int i = ty; i < 32; i += 8)
      Wt[(size_t)(c0 + i) * DDIM + r0 + tx] = f2b(tile[tx][i]);
    if(z == 0 && by == 0)
      rowsum[bx * 256 + tid] = 0.f;
  }
}

// ---------------- bf16 [b][t][d] -> [b][d][t] transpose ----------------
__global__ __launch_bounds__(256) void transpose_b16(const u16* __restrict__ X,
                                                     u16* __restrict__ Xt){
  __shared__ u16 tile[32][33];
  int b = blockIdx.z;
  const u16* src = X + (size_t)b * SEQ * DDIM;
  u16* dst = Xt + (size_t)b * SEQ * DDIM;
  int d0 = blockIdx.x * 32, t0 = blockIdx.y * 32;
  int tx = threadIdx.x;
  for(int i = threadIdx.y; i < 32; i += 8)
    tile[i][tx] = src[(size_t)(t0 + i) * DDIM + d0 + tx];
  __syncthreads();
  for(int i = threadIdx.y; i < 32; i += 8)
    dst[(size_t)(d0 + i) * SEQ + t0 + tx] = tile[tx][i];
}

// ============ phase-interleaved bf16 GEMM: C = epilogue(A[M,1024] . Bt[N,1024]^T) ============
// BM=256 BN=128 BK=64, 8 waves (4Mx2N), TRIPLE-buffered LDS, m201-style phases:
// per K-tile 2 phases, each {8 ds_read_b128 | stage-unit issue for t+2 | barrier |
// setprio + 16 indep MFMA + setprio | barrier}; counted vmcnt(6) once per tile at
// phase B (certifies tile t+1 across waves via the following barrier).
// XOR-swizzled LDS via pre-swizzled global source; bijective XCD swizzle.
// MODE 0: C = [relu](acc + bias)    -> bf16
// MODE 1: C = exp(acc) -> bf16, rowsum[bz*SEQ+row] += sum_cols exp (atomic)
// MODE 2: C = acc * (1/rowsum[row]) -> bf16
template<int MODE, bool RELU>
__global__ __launch_bounds__(512, 2) void gemm_bt(
    const u16* __restrict__ A, const u16* __restrict__ Bt,
    const float* __restrict__ bias, float* __restrict__ rowsum,
    u16* __restrict__ Cv,
    int gm, int N, long long bA, long long bB, long long bC)
{
  __shared__ u16 As[3][256][64];   // 96 KB
  __shared__ u16 Bs[3][128][64];   // 48 KB

  const int tid  = threadIdx.x;
  const int lane = tid & 63;
  const int wid  = tid >> 6;   // 0..7
  const int wr   = wid >> 1;   // 0..3 -> M
  const int wc   = wid & 1;    // 0..1 -> N

  // T1: bijective XCD swizzle (gridDim.x % 8 == 0 at all call sites)
  int id = blockIdx.x;
  const int chunk = gridDim.x >> 3;
  id = (id & 7) * chunk + (id >> 3);
  const int tn = id & 7;
  const int tm = (id >> 3) % gm;
  const int bz = (id >> 3) / gm;

  const char* gAp = (const char*)(A  + (size_t)bz * bA + (size_t)tm * 256 * GK);
  const char* gBp = (const char*)(Bt + (size_t)bz * bB + (size_t)tn * 128 * GK);
  // staging: thread covers row (q*64 + tid>>3), 16B chunk (tid&7); global col
  // pre-swizzled so the linear LDS dest realizes the XOR layout (rule 21).
  const int colg = ((tid & 7) * 16) ^ (((tid >> 3) & 7) << 4);
  const char* gA0 = gAp + (size_t)(tid >> 3) * 2048 + colg;
  const char* gB0 = gBp + (size_t)(tid >> 3) * 2048 + colg;
  char* lA0 = (char*)&As[0][0][0] + tid * 16;
  char* lB0 = (char*)&Bs[0][0][0] + tid * 16;
  const int SLA = 256 * 64 * 2;   // bytes per A slot
  const int SLB = 128 * 64 * 2;

  auto stageA = [&](int slot, int tt){   // 4 loads: A rows q*64+(tid>>3)
    const int g = tt * 128;
#pragma unroll
    for(int q = 0; q < 4; q++)
      load_lds16(gA0 + (size_t)q * 64 * 2048 + g, lA0 + slot * SLA + q * 8192);
  };
  auto stageB = [&](int slot, int tt){   // 2 loads
    const int g = tt * 128;
#pragma unroll
    for(int q = 0; q < 2; q++)
      load_lds16(gB0 + (size_t)q * 64 * 2048 + g, lB0 + slot * SLB + q * 8192);
  };

  f32x4 acc[4][4];
#pragma unroll
  for(int i = 0; i < 4; i++)
#pragma unroll
    for(int j = 0; j < 4; j++){ acc[i][j][0]=0.f; acc[i][j][1]=0.f; acc[i][j][2]=0.f; acc[i][j][3]=0.f; }

  const int fr = lane & 15, kq = lane >> 4;
  const int a0 = (kq * 16) ^ ((fr & 7) << 4);   // ks=0 byte offset within 128B row
  const int a1 = a0 ^ 64;                       // ks=1
  const char* aRd = (const char*)&As[0][0][0] + (wr * 64 + fr) * 128;
  const char* bRd = (const char*)&Bs[0][0][0] + (wc * 64 + fr) * 128;

  // ---- prologue: tiles 0,1 staged; certify tile 0 ----
  stageA(0, 0); stageB(0, 0);
  stageA(1, 1); stageB(1, 1);
  asm volatile("s_waitcnt vmcnt(6)" ::: "memory");   // 12 in flight -> tile0 landed
  SBAR();

  int slot = 0, slotp = 2;   // slotp = (t+2)%3
  for(int t = 0; t < NKT; ++t){
    const char* ab = aRd + slot * SLA;
    const char* bb = bRd + slot * SLB;
    bf16x8 av[4], bv[4];

    // -------- phase A (ks = 0) --------
#pragma unroll
    for(int mi = 0; mi < 4; mi++) av[mi] = *(const bf16x8*)(ab + mi * 2048 + a0);
#pragma unroll
    for(int ni = 0; ni < 4; ni++) bv[ni] = *(const bf16x8*)(bb + ni * 2048 + a0);
    if(t + 2 < NKT) stageA(slotp, t + 2);
    SBAR();
    __builtin_amdgcn_s_setprio(1);
#pragma unroll
    for(int mi = 0; mi < 4; mi++)
#pragma unroll
      for(int ni = 0; ni < 4; ni++)
        acc[mi][ni] = __builtin_amdgcn_mfma_f32_16x16x32_bf16(av[mi], bv[ni], acc[mi][ni], 0, 0, 0);
    __builtin_amdgcn_s_setprio(0);
    SBAR();

    // -------- phase B (ks = 1) --------
#pragma unroll
    for(int mi = 0; mi < 4; mi++) av[mi] = *(const bf16x8*)(ab + mi * 2048 + a1);
#pragma unroll
    for(int ni = 0; ni < 4; ni++) bv[ni] = *(const bf16x8*)(bb + ni * 2048 + a1);
    if(t + 2 < NKT) stageB(slotp, t + 2);
    if(t < NKT - 2){ asm volatile("s_waitcnt vmcnt(6)" ::: "memory"); }
    else if(t == NKT - 2){ asm volatile("s_waitcnt vmcnt(0)" ::: "memory"); }
    SBAR();   // certifies (with the vmcnt above) tile t+1 landed for ALL waves
    __builtin_amdgcn_s_setprio(1);
#pragma unroll
    for(int mi = 0; mi < 4; mi++)
#pragma unroll
      for(int ni = 0; ni < 4; ni++)
        acc[mi][ni] = __builtin_amdgcn_mfma_f32_16x16x32_bf16(av[mi], bv[ni], acc[mi][ni], 0, 0, 0);
    __builtin_amdgcn_s_setprio(0);
    SBAR();

    slot  = (slot  == 2) ? 0 : slot  + 1;
    slotp = (slotp == 2) ? 0 : slotp + 1;
  }

  // ---- epilogue: C/D layout col=lane&15, row=(lane>>4)*4+reg ----
  const int m0 = tm * 256 + wr * 64;
  const int n0 = tn * 128 + wc * 64;
  const int rq = lane >> 4;

  if(MODE == 0){
#pragma unroll
    for(int ni = 0; ni < 4; ni++){
      const int gcol = n0 + ni * 16 + fr;
      const float bv = bias[gcol];
#pragma unroll
      for(int mi = 0; mi < 4; mi++){
#pragma unroll
        for(int r = 0; r < 4; r++){
          const int grow = m0 + mi * 16 + rq * 4 + r;
          float v = acc[mi][ni][r] + bv;
          if(RELU) v = fmaxf(v, 0.f);
          Cv[(size_t)bz * bC + (size_t)grow * N + gcol] = f2b(v);
        }
      }
    }
  } else if(MODE == 1){
    float rs[4][4];
#pragma unroll
    for(int mi = 0; mi < 4; mi++)
#pragma unroll
      for(int r = 0; r < 4; r++) rs[mi][r] = 0.f;
#pragma unroll
    for(int ni = 0; ni < 4; ni++){
      const int gcol = n0 + ni * 16 + fr;
#pragma unroll
      for(int mi = 0; mi < 4; mi++){
#pragma unroll
        for(int r = 0; r < 4; r++){
          const int grow = m0 + mi * 16 + rq * 4 + r;
          float e = __expf(acc[mi][ni][r]);
          rs[mi][r] += e;
          Cv[(size_t)bz * bC + (size_t)grow * N + gcol] = f2b(e);
        }
      }
    }
#pragma unroll
    for(int off = 1; off < 16; off <<= 1)
#pragma unroll
      for(int mi = 0; mi < 4; mi++)
#pragma unroll
        for(int r = 0; r < 4; r++) rs[mi][r] += __shfl_xor(rs[mi][r], off);
    if(fr == 0){
#pragma unroll
      for(int mi = 0; mi < 4; mi++)
#pragma unroll
        for(int r = 0; r < 4; r++){
          const int grow = m0 + mi * 16 + rq * 4 + r;
          atomicAdd(&rowsum[bz * SEQ + grow], rs[mi][r]);
        }
    }
  } else {
    float inv[4][4];
#pragma unroll
    for(int mi = 0; mi < 4; mi++)
#pragma unroll
      for(int r = 0; r < 4; r++){
        const int grow = m0 + mi * 16 + rq * 4 + r;
        inv[mi][r] = __builtin_amdgcn_rcpf(rowsum[bz * SEQ + grow]);
      }
#pragma unroll
    for(int ni = 0; ni < 4; ni++){
      const int gcol = n0 + ni * 16 + fr;
#pragma unroll
      for(int mi = 0; mi < 4; mi++){
#pragma unroll
        for(int r = 0; r < 4; r++){
          const int grow = m0 + mi * 16 + rq * 4 + r;
          Cv[(size_t)bz * bC + (size_t)grow * N + gcol] = f2b(acc[mi][ni][r] * inv[mi][r]);
        }
      }
    }
  }
}

// ---------------- em = [p_cla | out2] @ W_hid + b_hid ----------------
__global__ __launch_bounds__(256) void em_kernel(const u16* __restrict__ out2,
                                                 const float* __restrict__ pcla,
                                                 const float* __restrict__ Whid,
                                                 const float* __restrict__ bhid,
                                                 float* __restrict__ em){
  const int row  = blockIdx.x * 4 + (threadIdx.x >> 6);
  const int lane = threadIdx.x & 63;
  float s[8] = {0.f,0.f,0.f,0.f,0.f,0.f,0.f,0.f};
  const u16* o2 = out2 + (size_t)row * 1024 + lane * 16;
#pragma unroll
  for(int h = 0; h < 2; h++){
    bf16x8 v = *(const bf16x8*)(o2 + h * 8);
#pragma unroll
    for(int e = 0; e < 8; e++){
      const float od = b2f((u16)v[e]);
      const int d = lane * 16 + h * 8 + e;
      const float* wr = Whid + (size_t)(NP + d) * 8;
#pragma unroll
      for(int j = 0; j < 8; j++) s[j] += od * wr[j];
    }
  }
#pragma unroll
  for(int q = 0; q < 2; q++){
    const int p = lane * 2 + q;
    const float pv = pcla[(size_t)row * NP + p];
    const float* wr = Whid + (size_t)p * 8;
#pragma unroll
    for(int j = 0; j < 8; j++) s[j] += pv * wr[j];
  }
#pragma unroll
  for(int off = 1; off < 64; off <<= 1)
#pragma unroll
    for(int j = 0; j < 8; j++) s[j] += __shfl_xor(s[j], off);
  if(lane == 0){
#pragma unroll
    for(int j = 0; j < 8; j++) em[(size_t)row * 8 + j] = s[j] + bhid[j];
  }
}

// ---------------- CRF NLL per batch (prob-domain chunked scan + tree) ----------------
__global__ __launch_bounds__(256) void crf_kernel(const float* __restrict__ em,
                                                  const int* __restrict__ tags,
                                                  const float* __restrict__ cstart,
                                                  const float* __restrict__ cend,
                                                  const float* __restrict__ ctrans,
                                                  float* __restrict__ partial){
  const int b = blockIdx.x;
  const int tid = threadIdx.x;
  const float* emb = em + (size_t)b * SEQ * 8;
  const int* tg = tags + b * SEQ;

  __shared__ float Mbuf[128][64];
  __shared__ float Mbuf2[64][64];
  __shared__ float ls1[128], ls2[64];
  __shared__ float etr_s[64];
  __shared__ float mxs[64];
  __shared__ float red[256];

  if(tid < 64) etr_s[tid] = expf(ctrans[tid]);

  float loc = 0.f;
  for(int t = tid; t < SEQ; t += 256){
    const int tgt = tg[t];
    loc += emb[t * 8 + tgt];
    if(t < SEQ - 1) loc += ctrans[tgt * 8 + tg[t + 1]];
  }
  if(tid == 0) loc += cstart[tg[0]] + cend[tg[SEQ - 1]];
  red[tid] = loc;
  __syncthreads();
  for(int s = 128; s > 0; s >>= 1){
    if(tid < s) red[tid] += red[tid + s];
    __syncthreads();
  }

  if(tid < 128){
    const int c = tid;
    const int t0 = (c == 0) ? 1 : c * 8;
    const int t1 = c * 8 + 8;
    float etr[64];
#pragma unroll
    for(int i = 0; i < 64; i++) etr[i] = etr_s[i];
    float acc[64];
    float ej[8];
#pragma unroll
    for(int j = 0; j < 8; j++) ej[j] = expf(emb[t0 * 8 + j]);
#pragma unroll
    for(int i = 0; i < 8; i++)
#pragma unroll
      for(int j = 0; j < 8; j++) acc[i * 8 + j] = etr[i * 8 + j] * ej[j];
    for(int t = t0 + 1; t < t1; t++){
#pragma unroll
      for(int j = 0; j < 8; j++) ej[j] = expf(emb[t * 8 + j]);
#pragma unroll
      for(int i = 0; i < 8; i++){
        float tmp[8];
#pragma unroll
        for(int j = 0; j < 8; j++){
          float sv = 0.f;
#pragma unroll
          for(int k = 0; k < 8; k++) sv += acc[i * 8 + k] * etr[k * 8 + j];
          tmp[j] = sv * ej[j];
        }
#pragma unroll
        for(int j = 0; j < 8; j++) acc[i * 8 + j] = tmp[j];
      }
    }
    float mx = acc[0];
#pragma unroll
    for(int i = 1; i < 64; i++) mx = fmaxf(mx, acc[i]);
    const float im = 1.f / mx;
#pragma unroll
    for(int i = 0; i < 64; i++) Mbuf[c][i] = acc[i] * im;
    ls1[c] = logf(mx);
  }
  __syncthreads();

  float* src = &Mbuf[0][0];  float* dst = &Mbuf2[0][0];
  float* lsrc = ls1;         float* ldst = ls2;
  for(int n = 64; n >= 1; n >>= 1){
    for(int idx = tid; idx < n * 64; idx += 256){
      const int p = idx >> 6, e = idx & 63, i = e >> 3, j = e & 7;
      const float* Am = src + (size_t)(2 * p) * 64;
      const float* Bm = src + (size_t)(2 * p + 1) * 64;
      float sv = 0.f;
#pragma unroll
      for(int k = 0; k < 8; k++) sv += Am[i * 8 + k] * Bm[k * 8 + j];
      dst[(size_t)p * 64 + e] = sv;
    }
    __syncthreads();
    if(tid < n){
      const float* Cm = dst + (size_t)tid * 64;
      float mx = Cm[0];
#pragma unroll
      for(int i = 1; i < 64; i++) mx = fmaxf(mx, Cm[i]);
      mxs[tid] = 1.f / mx;
      ldst[tid] = lsrc[2 * tid] + lsrc[2 * tid + 1] + logf(mx);
    }
    __syncthreads();
    for(int idx = tid; idx < n * 64; idx += 256)
      dst[idx] *= mxs[idx >> 6];
    __syncthreads();
    float* tf = src; src = dst; dst = tf;
    float* tl = lsrc; lsrc = ldst; ldst = tl;
  }

  if(tid == 0){
    float a0[8];
#pragma unroll
    for(int i = 0; i < 8; i++) a0[i] = expf(cstart[i] + emb[i]);
    float z = 0.f;
#pragma unroll
    for(int j = 0; j < 8; j++){
      float t = 0.f;
#pragma unroll
      for(int i = 0; i < 8; i++) t += a0[i] * src[i * 8 + j];
      z += t * expf(cend[j]);
    }
    const float logZ = logf(z) + lsrc[0];
    partial[b] = logZ - red[0];
  }
}

__global__ void final_sum(const float* __restrict__ partial, float* __restrict__ out){
  if(threadIdx.x == 0){
    float s = 0.f;
    for(int b = 0; b < NB; b++) s += partial[b];
    out[0] = s;
  }
}

// ---------------- launch ----------------
extern "C" void kernel_launch(void* const* d_in, const int* in_sizes, int n_in,
                              void* d_out, int out_size, void* d_ws, size_t ws_size,
                              hipStream_t stream){
  (void)in_sizes; (void)n_in; (void)out_size; (void)ws_size;
  const float* x      = (const float*)d_in[0];
  const float* p_cla  = (const float*)d_in[1];
  const float* W_emo  = (const float*)d_in[2];
  const float* b_emo  = (const float*)d_in[3];
  const float* W_att  = (const float*)d_in[4];
  const float* b_att  = (const float*)d_in[5];
  const float* W_hid  = (const float*)d_in[6];
  const float* b_hid  = (const float*)d_in[7];
  const float* cstart = (const float*)d_in[8];
  const float* cend   = (const float*)d_in[9];
  const float* ctrans = (const float*)d_in[10];
  const int*   tags   = (const int*)d_in[11];

  char* ws = (char*)d_ws;
  const size_t MB = 1u << 20;
  u16*   xb     = (u16*)(ws + 0 * MB);        // 16MB
  u16*   wemoT  = (u16*)(ws + 16 * MB);       // 2MB
  u16*   wattT  = (u16*)(ws + 18 * MB);       // 2MB
  u16*   out_b  = (u16*)(ws + 20 * MB);       // 16MB
  u16*   outT   = (u16*)(ws + 36 * MB);       // 16MB
  u16*   oatt   = (u16*)(ws + 52 * MB);       // 16MB
  u16*   scores = (u16*)(ws + 68 * MB);       // 16MB (unnormalized exp, bf16)
  u16*   out2   = (u16*)(ws + 84 * MB);       // 16MB
  float* em     = (float*)(ws + 100 * MB);    // 256KB
  float* part   = (float*)(ws + 100 * MB + 262144);
  float* rowsum = (float*)(ws + 100 * MB + 524288);  // 32KB

  const long long bs = (long long)SEQ * DDIM;

  // convert x + transpose both weights + zero rowsum, one launch
  prep_kernel<<<8192 + 2048, 256, 0, stream>>>(x, xb, W_emo, W_att, wemoT, wattT, rowsum);

  // out = relu(x @ W_emo + b_emo) ; grid = gm*gn*gb = 32*8*1 = 256
  gemm_bt<0, true><<<256, 512, 0, stream>>>(
      xb, wemoT, b_emo, nullptr, out_b, 32, DDIM, 0, 0, 0);
  // V^T for PV
  transpose_b16<<<dim3(32, 32, NB), dim3(32, 8), 0, stream>>>(out_b, outT);
  // out_att = out @ W_att + b_att
  gemm_bt<0, false><<<256, 512, 0, stream>>>(
      out_b, wattT, b_att, nullptr, oatt, 32, DDIM, 0, 0, 0);
  // scores[b] = exp(out_att[b] @ out[b]^T) (bf16) + rowsum atomics ; 4*8*8 = 256
  gemm_bt<1, false><<<256, 512, 0, stream>>>(
      oatt, out_b, nullptr, rowsum, scores, 4, SEQ, bs, bs, bs);
  // out2[b] = (scores[b] @ out[b]) / rowsum
  gemm_bt<2, false><<<256, 512, 0, stream>>>(
      scores, outT, nullptr, rowsum, out2, 4, SEQ, bs, bs, bs);
  // em = [p_cla | out2] @ W_hid + b_hid
  em_kernel<<<2048, 256, 0, stream>>>(out2, p_cla, W_hid, b_hid, em);
  // CRF NLL
  crf_kernel<<<NB, 256, 0, stream>>>(em, tags, cstart, cend, ctrans, part);
  final_sum<<<1, 64, 0, stream>>>(part, (float*)d_out);
}

// Round 6
// 165.307 us; speedup vs baseline: 1.2995x; 1.0564x over previous
//
#include <hip/hip_runtime.h>
#include <stdint.h>

typedef unsigned short u16;
typedef __attribute__((ext_vector_type(8))) short bf16x8;
typedef __attribute__((ext_vector_type(4))) float f32x4;

#define NB 8
#define SEQ 1024
#define DDIM 1024
#define NP 128
#define NT 8
#define GK 1024           // K for all GEMMs
#define NKT 16            // GK/64

__device__ __forceinline__ u16 f2b(float f){
  union { float f; uint32_t u; } v; v.f = f;
  return (u16)((v.u + 0x7FFFu + ((v.u >> 16) & 1u)) >> 16);
}
__device__ __forceinline__ float b2f(u16 h){
  union { uint32_t u; float f; } v; v.u = ((uint32_t)h) << 16; return v.f;
}

__device__ __forceinline__ void load_lds16(const void* g, void* l){
  __builtin_amdgcn_global_load_lds((const __attribute__((address_space(1))) void*)g,
                                   (__attribute__((address_space(3))) void*)l,
                                   16, 0, 0);
}

#define MEMFENCE asm volatile("" ::: "memory")
#define SBAR() do { MEMFENCE; __builtin_amdgcn_s_barrier(); MEMFENCE; } while(0)

// ------- merged prep: f32->bf16 convert of x  +  2 weight transposes + rowsum zero -------
__global__ __launch_bounds__(256) void prep_kernel(const float* __restrict__ x,
                                                   u16* __restrict__ xb,
                                                   const float* __restrict__ W0,
                                                   const float* __restrict__ W1,
                                                   u16* __restrict__ T0,
                                                   u16* __restrict__ T1,
                                                   float* __restrict__ rowsum){
  __shared__ float tile[32][33];
  const int bid = blockIdx.x;
  const int tid = threadIdx.x;
  if(bid < 8192){
    int idx = (bid * 256 + tid) * 4;
    float4 v = *(const float4*)(x + idx);
    ushort4 o;
    o.x = f2b(v.x); o.y = f2b(v.y); o.z = f2b(v.z); o.w = f2b(v.w);
    *(ushort4*)(xb + idx) = o;
  } else {
    const int b2 = bid - 8192;                 // 0..2047
    const int z  = b2 >> 10;                   // 0/1 -> which weight
    const int bx = b2 & 31, by = (b2 >> 5) & 31;
    const int tx = tid & 31, ty = tid >> 5;    // 32 x 8
    const float* W = z ? W1 : W0;
    u16* Wt = z ? T1 : T0;
    const int c0 = bx * 32, r0 = by * 32;
    for(int i = ty; i < 32; i += 8)
      tile[i][tx] = W[(size_t)(r0 + i) * DDIM + c0 + tx];
    __syncthreads();
    for(int i = ty; i < 32; i += 8)
      Wt[(size_t)(c0 + i) * DDIM + r0 + tx] = f2b(tile[tx][i]);
    if(z == 0 && by == 0)
      rowsum[bx * 256 + tid] = 0.f;
  }
}

// ---------------- bf16 [b][t][d] -> [b][d][t] transpose ----------------
__global__ __launch_bounds__(256) void transpose_b16(const u16* __restrict__ X,
                                                     u16* __restrict__ Xt){
  __shared__ u16 tile[32][33];
  int b = blockIdx.z;
  const u16* src = X + (size_t)b * SEQ * DDIM;
  u16* dst = Xt + (size_t)b * SEQ * DDIM;
  int d0 = blockIdx.x * 32, t0 = blockIdx.y * 32;
  int tx = threadIdx.x;
  for(int i = threadIdx.y; i < 32; i += 8)
    tile[i][tx] = src[(size_t)(t0 + i) * DDIM + d0 + tx];
  __syncthreads();
  for(int i = threadIdx.y; i < 32; i += 8)
    dst[(size_t)(d0 + i) * SEQ + t0 + tx] = tile[tx][i];
}

// ============ minimal-barrier pipelined bf16 GEMM: C = epilogue(A[M,1024] . Bt[N,1024]^T) ============
// BM=256 BN=128 BK=64, 8 waves (4Mx2N), TRIPLE-buffered LDS.
// ONE barrier + ONE counted vmcnt per K-tile; waves free-run within the tile
// (ds_reads of one wave overlap MFMA of another; setprio arbitrates).
// Hazard ledger: (1) reads of tile t gated by top-of-t vmcnt(6)+barrier (per-wave
// vmcnt made collective by the barrier); (2) stage during t targets slot((t+2)%3)
// = slot read in t-1; every wave's t-1 ds_reads are complete before it passes the
// t-top barrier (each read is consumed by an MFMA in t-1's body), so no overwrite
// hazard. XOR-swizzled LDS via pre-swizzled global source; bijective XCD swizzle.
// MODE 0: C = [relu](acc + bias)    -> bf16
// MODE 1: C = exp(acc) -> bf16, rowsum[bz*SEQ+row] += sum_cols exp (atomic)
// MODE 2: C = acc * (1/rowsum[row]) -> bf16
template<int MODE, bool RELU>
__global__ __launch_bounds__(512, 2) void gemm_bt(
    const u16* __restrict__ A, const u16* __restrict__ Bt,
    const float* __restrict__ bias, float* __restrict__ rowsum,
    u16* __restrict__ Cv,
    int gm, int N, long long bA, long long bB, long long bC)
{
  __shared__ u16 As[3][256][64];   // 96 KB
  __shared__ u16 Bs[3][128][64];   // 48 KB

  const int tid  = threadIdx.x;
  const int lane = tid & 63;
  const int wid  = tid >> 6;   // 0..7
  const int wr   = wid >> 1;   // 0..3 -> M
  const int wc   = wid & 1;    // 0..1 -> N

  // T1: bijective XCD swizzle (gridDim.x % 8 == 0 at all call sites)
  int id = blockIdx.x;
  const int chunk = gridDim.x >> 3;
  id = (id & 7) * chunk + (id >> 3);
  const int tn = id & 7;
  const int tm = (id >> 3) % gm;
  const int bz = (id >> 3) / gm;

  const char* gAp = (const char*)(A  + (size_t)bz * bA + (size_t)tm * 256 * GK);
  const char* gBp = (const char*)(Bt + (size_t)bz * bB + (size_t)tn * 128 * GK);
  // staging: thread covers row (q*64 + tid>>3), 16B chunk (tid&7); global col
  // pre-swizzled so the linear LDS dest realizes the XOR layout (rule 21).
  const int colg = ((tid & 7) * 16) ^ (((tid >> 3) & 7) << 4);
  const char* gA0 = gAp + (size_t)(tid >> 3) * 2048 + colg;
  const char* gB0 = gBp + (size_t)(tid >> 3) * 2048 + colg;
  char* lA0 = (char*)&As[0][0][0] + tid * 16;
  char* lB0 = (char*)&Bs[0][0][0] + tid * 16;
  const int SLA = 256 * 64 * 2;   // bytes per A slot
  const int SLB = 128 * 64 * 2;

  auto stageA = [&](int slot, int tt){   // 4 loads
    const int g = tt * 128;
#pragma unroll
    for(int q = 0; q < 4; q++)
      load_lds16(gA0 + (size_t)q * 64 * 2048 + g, lA0 + slot * SLA + q * 8192);
  };
  auto stageB = [&](int slot, int tt){   // 2 loads
    const int g = tt * 128;
#pragma unroll
    for(int q = 0; q < 2; q++)
      load_lds16(gB0 + (size_t)q * 64 * 2048 + g, lB0 + slot * SLB + q * 8192);
  };

  f32x4 acc[4][4];
#pragma unroll
  for(int i = 0; i < 4; i++)
#pragma unroll
    for(int j = 0; j < 4; j++){ acc[i][j][0]=0.f; acc[i][j][1]=0.f; acc[i][j][2]=0.f; acc[i][j][3]=0.f; }

  const int fr = lane & 15, kq = lane >> 4;
  const int a0 = (kq * 16) ^ ((fr & 7) << 4);   // ks=0 byte offset within 128B row
  const int a1 = a0 ^ 64;                       // ks=1
  const char* aRd = (const char*)&As[0][0][0] + (wr * 64 + fr) * 128;
  const char* bRd = (const char*)&Bs[0][0][0] + (wc * 64 + fr) * 128;

  // ---- prologue: stage tiles 0,1 (12 loads in flight) ----
  stageA(0, 0); stageB(0, 0);
  stageA(1, 1); stageB(1, 1);

  int slot = 0, slotp = 2;   // slotp = (t+2)%3
  for(int t = 0; t < NKT; ++t){
    if(t < NKT - 1){ asm volatile("s_waitcnt vmcnt(6)" ::: "memory"); }
    else           { asm volatile("s_waitcnt vmcnt(0)" ::: "memory"); }
    SBAR();   // collective: tile t staged for ALL waves; tile t-1 reads all done

    const char* ab = aRd + slot * SLA;
    const char* bb = bRd + slot * SLB;
    bf16x8 av[4], bv[4], aw[4], bw[4];
#pragma unroll
    for(int mi = 0; mi < 4; mi++) av[mi] = *(const bf16x8*)(ab + mi * 2048 + a0);
#pragma unroll
    for(int ni = 0; ni < 4; ni++) bv[ni] = *(const bf16x8*)(bb + ni * 2048 + a0);
#pragma unroll
    for(int mi = 0; mi < 4; mi++) aw[mi] = *(const bf16x8*)(ab + mi * 2048 + a1);
#pragma unroll
    for(int ni = 0; ni < 4; ni++) bw[ni] = *(const bf16x8*)(bb + ni * 2048 + a1);
    if(t + 2 < NKT){ stageA(slotp, t + 2); stageB(slotp, t + 2); }

    __builtin_amdgcn_s_setprio(1);
#pragma unroll
    for(int mi = 0; mi < 4; mi++)
#pragma unroll
      for(int ni = 0; ni < 4; ni++)
        acc[mi][ni] = __builtin_amdgcn_mfma_f32_16x16x32_bf16(av[mi], bv[ni], acc[mi][ni], 0, 0, 0);
#pragma unroll
    for(int mi = 0; mi < 4; mi++)
#pragma unroll
      for(int ni = 0; ni < 4; ni++)
        acc[mi][ni] = __builtin_amdgcn_mfma_f32_16x16x32_bf16(aw[mi], bw[ni], acc[mi][ni], 0, 0, 0);
    __builtin_amdgcn_s_setprio(0);

    slot  = (slot  == 2) ? 0 : slot  + 1;
    slotp = (slotp == 2) ? 0 : slotp + 1;
  }

  // ---- epilogue: C/D layout col=lane&15, row=(lane>>4)*4+reg ----
  const int m0 = tm * 256 + wr * 64;
  const int n0 = tn * 128 + wc * 64;
  const int rq = lane >> 4;

  if(MODE == 0){
#pragma unroll
    for(int ni = 0; ni < 4; ni++){
      const int gcol = n0 + ni * 16 + fr;
      const float bv = bias[gcol];
#pragma unroll
      for(int mi = 0; mi < 4; mi++){
#pragma unroll
        for(int r = 0; r < 4; r++){
          const int grow = m0 + mi * 16 + rq * 4 + r;
          float v = acc[mi][ni][r] + bv;
          if(RELU) v = fmaxf(v, 0.f);
          Cv[(size_t)bz * bC + (size_t)grow * N + gcol] = f2b(v);
        }
      }
    }
  } else if(MODE == 1){
    float rs[4][4];
#pragma unroll
    for(int mi = 0; mi < 4; mi++)
#pragma unroll
      for(int r = 0; r < 4; r++) rs[mi][r] = 0.f;
#pragma unroll
    for(int ni = 0; ni < 4; ni++){
      const int gcol = n0 + ni * 16 + fr;
#pragma unroll
      for(int mi = 0; mi < 4; mi++){
#pragma unroll
        for(int r = 0; r < 4; r++){
          const int grow = m0 + mi * 16 + rq * 4 + r;
          float e = __expf(acc[mi][ni][r]);
          rs[mi][r] += e;
          Cv[(size_t)bz * bC + (size_t)grow * N + gcol] = f2b(e);
        }
      }
    }
#pragma unroll
    for(int off = 1; off < 16; off <<= 1)
#pragma unroll
      for(int mi = 0; mi < 4; mi++)
#pragma unroll
        for(int r = 0; r < 4; r++) rs[mi][r] += __shfl_xor(rs[mi][r], off);
    if(fr == 0){
#pragma unroll
      for(int mi = 0; mi < 4; mi++)
#pragma unroll
        for(int r = 0; r < 4; r++){
          const int grow = m0 + mi * 16 + rq * 4 + r;
          atomicAdd(&rowsum[bz * SEQ + grow], rs[mi][r]);
        }
    }
  } else {
    float inv[4][4];
#pragma unroll
    for(int mi = 0; mi < 4; mi++)
#pragma unroll
      for(int r = 0; r < 4; r++){
        const int grow = m0 + mi * 16 + rq * 4 + r;
        inv[mi][r] = __builtin_amdgcn_rcpf(rowsum[bz * SEQ + grow]);
      }
#pragma unroll
    for(int ni = 0; ni < 4; ni++){
      const int gcol = n0 + ni * 16 + fr;
#pragma unroll
      for(int mi = 0; mi < 4; mi++){
#pragma unroll
        for(int r = 0; r < 4; r++){
          const int grow = m0 + mi * 16 + rq * 4 + r;
          Cv[(size_t)bz * bC + (size_t)grow * N + gcol] = f2b(acc[mi][ni][r] * inv[mi][r]);
        }
      }
    }
  }
}

// ---------------- em = [p_cla | out2] @ W_hid + b_hid ----------------
__global__ __launch_bounds__(256) void em_kernel(const u16* __restrict__ out2,
                                                 const float* __restrict__ pcla,
                                                 const float* __restrict__ Whid,
                                                 const float* __restrict__ bhid,
                                                 float* __restrict__ em){
  const int row  = blockIdx.x * 4 + (threadIdx.x >> 6);
  const int lane = threadIdx.x & 63;
  float s[8] = {0.f,0.f,0.f,0.f,0.f,0.f,0.f,0.f};
  const u16* o2 = out2 + (size_t)row * 1024 + lane * 16;
#pragma unroll
  for(int h = 0; h < 2; h++){
    bf16x8 v = *(const bf16x8*)(o2 + h * 8);
#pragma unroll
    for(int e = 0; e < 8; e++){
      const float od = b2f((u16)v[e]);
      const int d = lane * 16 + h * 8 + e;
      const float* wr = Whid + (size_t)(NP + d) * 8;
#pragma unroll
      for(int j = 0; j < 8; j++) s[j] += od * wr[j];
    }
  }
#pragma unroll
  for(int q = 0; q < 2; q++){
    const int p = lane * 2 + q;
    const float pv = pcla[(size_t)row * NP + p];
    const float* wr = Whid + (size_t)p * 8;
#pragma unroll
    for(int j = 0; j < 8; j++) s[j] += pv * wr[j];
  }
#pragma unroll
  for(int off = 1; off < 64; off <<= 1)
#pragma unroll
    for(int j = 0; j < 8; j++) s[j] += __shfl_xor(s[j], off);
  if(lane == 0){
#pragma unroll
    for(int j = 0; j < 8; j++) em[(size_t)row * 8 + j] = s[j] + bhid[j];
  }
}

// ---------------- CRF NLL per batch (prob-domain chunked scan + tree) ----------------
__global__ __launch_bounds__(256) void crf_kernel(const float* __restrict__ em,
                                                  const int* __restrict__ tags,
                                                  const float* __restrict__ cstart,
                                                  const float* __restrict__ cend,
                                                  const float* __restrict__ ctrans,
                                                  float* __restrict__ partial){
  const int b = blockIdx.x;
  const int tid = threadIdx.x;
  const float* emb = em + (size_t)b * SEQ * 8;
  const int* tg = tags + b * SEQ;

  __shared__ float Mbuf[128][64];
  __shared__ float Mbuf2[64][64];
  __shared__ float ls1[128], ls2[64];
  __shared__ float etr_s[64];
  __shared__ float mxs[64];
  __shared__ float red[256];

  if(tid < 64) etr_s[tid] = expf(ctrans[tid]);

  float loc = 0.f;
  for(int t = tid; t < SEQ; t += 256){
    const int tgt = tg[t];
    loc += emb[t * 8 + tgt];
    if(t < SEQ - 1) loc += ctrans[tgt * 8 + tg[t + 1]];
  }
  if(tid == 0) loc += cstart[tg[0]] + cend[tg[SEQ - 1]];
  red[tid] = loc;
  __syncthreads();
  for(int s = 128; s > 0; s >>= 1){
    if(tid < s) red[tid] += red[tid + s];
    __syncthreads();
  }

  if(tid < 128){
    const int c = tid;
    const int t0 = (c == 0) ? 1 : c * 8;
    const int t1 = c * 8 + 8;
    float etr[64];
#pragma unroll
    for(int i = 0; i < 64; i++) etr[i] = etr_s[i];
    float acc[64];
    float ej[8];
#pragma unroll
    for(int j = 0; j < 8; j++) ej[j] = expf(emb[t0 * 8 + j]);
#pragma unroll
    for(int i = 0; i < 8; i++)
#pragma unroll
      for(int j = 0; j < 8; j++) acc[i * 8 + j] = etr[i * 8 + j] * ej[j];
    for(int t = t0 + 1; t < t1; t++){
#pragma unroll
      for(int j = 0; j < 8; j++) ej[j] = expf(emb[t * 8 + j]);
#pragma unroll
      for(int i = 0; i < 8; i++){
        float tmp[8];
#pragma unroll
        for(int j = 0; j < 8; j++){
          float sv = 0.f;
#pragma unroll
          for(int k = 0; k < 8; k++) sv += acc[i * 8 + k] * etr[k * 8 + j];
          tmp[j] = sv * ej[j];
        }
#pragma unroll
        for(int j = 0; j < 8; j++) acc[i * 8 + j] = tmp[j];
      }
    }
    float mx = acc[0];
#pragma unroll
    for(int i = 1; i < 64; i++) mx = fmaxf(mx, acc[i]);
    const float im = 1.f / mx;
#pragma unroll
    for(int i = 0; i < 64; i++) Mbuf[c][i] = acc[i] * im;
    ls1[c] = logf(mx);
  }
  __syncthreads();

  float* src = &Mbuf[0][0];  float* dst = &Mbuf2[0][0];
  float* lsrc = ls1;         float* ldst = ls2;
  for(int n = 64; n >= 1; n >>= 1){
    for(int idx = tid; idx < n * 64; idx += 256){
      const int p = idx >> 6, e = idx & 63, i = e >> 3, j = e & 7;
      const float* Am = src + (size_t)(2 * p) * 64;
      const float* Bm = src + (size_t)(2 * p + 1) * 64;
      float sv = 0.f;
#pragma unroll
      for(int k = 0; k < 8; k++) sv += Am[i * 8 + k] * Bm[k * 8 + j];
      dst[(size_t)p * 64 + e] = sv;
    }
    __syncthreads();
    if(tid < n){
      const float* Cm = dst + (size_t)tid * 64;
      float mx = Cm[0];
#pragma unroll
      for(int i = 1; i < 64; i++) mx = fmaxf(mx, Cm[i]);
      mxs[tid] = 1.f / mx;
      ldst[tid] = lsrc[2 * tid] + lsrc[2 * tid + 1] + logf(mx);
    }
    __syncthreads();
    for(int idx = tid; idx < n * 64; idx += 256)
      dst[idx] *= mxs[idx >> 6];
    __syncthreads();
    float* tf = src; src = dst; dst = tf;
    float* tl = lsrc; lsrc = ldst; ldst = tl;
  }

  if(tid == 0){
    float a0[8];
#pragma unroll
    for(int i = 0; i < 8; i++) a0[i] = expf(cstart[i] + emb[i]);
    float z = 0.f;
#pragma unroll
    for(int j = 0; j < 8; j++){
      float t = 0.f;
#pragma unroll
      for(int i = 0; i < 8; i++) t += a0[i] * src[i * 8 + j];
      z += t * expf(cend[j]);
    }
    const float logZ = logf(z) + lsrc[0];
    partial[b] = logZ - red[0];
  }
}

__global__ void final_sum(const float* __restrict__ partial, float* __restrict__ out){
  if(threadIdx.x == 0){
    float s = 0.f;
    for(int b = 0; b < NB; b++) s += partial[b];
    out[0] = s;
  }
}

// ---------------- launch ----------------
extern "C" void kernel_launch(void* const* d_in, const int* in_sizes, int n_in,
                              void* d_out, int out_size, void* d_ws, size_t ws_size,
                              hipStream_t stream){
  (void)in_sizes; (void)n_in; (void)out_size; (void)ws_size;
  const float* x      = (const float*)d_in[0];
  const float* p_cla  = (const float*)d_in[1];
  const float* W_emo  = (const float*)d_in[2];
  const float* b_emo  = (const float*)d_in[3];
  const float* W_att  = (const float*)d_in[4];
  const float* b_att  = (const float*)d_in[5];
  const float* W_hid  = (const float*)d_in[6];
  const float* b_hid  = (const float*)d_in[7];
  const float* cstart = (const float*)d_in[8];
  const float* cend   = (const float*)d_in[9];
  const float* ctrans = (const float*)d_in[10];
  const int*   tags   = (const int*)d_in[11];

  char* ws = (char*)d_ws;
  const size_t MB = 1u << 20;
  u16*   xb     = (u16*)(ws + 0 * MB);        // 16MB
  u16*   wemoT  = (u16*)(ws + 16 * MB);       // 2MB
  u16*   wattT  = (u16*)(ws + 18 * MB);       // 2MB
  u16*   out_b  = (u16*)(ws + 20 * MB);       // 16MB
  u16*   outT   = (u16*)(ws + 36 * MB);       // 16MB
  u16*   oatt   = (u16*)(ws + 52 * MB);       // 16MB
  u16*   scores = (u16*)(ws + 68 * MB);       // 16MB (unnormalized exp, bf16)
  u16*   out2   = (u16*)(ws + 84 * MB);       // 16MB
  float* em     = (float*)(ws + 100 * MB);    // 256KB
  float* part   = (float*)(ws + 100 * MB + 262144);
  float* rowsum = (float*)(ws + 100 * MB + 524288);  // 32KB

  const long long bs = (long long)SEQ * DDIM;

  // convert x + transpose both weights + zero rowsum, one launch
  prep_kernel<<<8192 + 2048, 256, 0, stream>>>(x, xb, W_emo, W_att, wemoT, wattT, rowsum);

  // out = relu(x @ W_emo + b_emo) ; grid = gm*gn*gb = 32*8*1 = 256
  gemm_bt<0, true><<<256, 512, 0, stream>>>(
      xb, wemoT, b_emo, nullptr, out_b, 32, DDIM, 0, 0, 0);
  // V^T for PV
  transpose_b16<<<dim3(32, 32, NB), dim3(32, 8), 0, stream>>>(out_b, outT);
  // out_att = out @ W_att + b_att
  gemm_bt<0, false><<<256, 512, 0, stream>>>(
      out_b, wattT, b_att, nullptr, oatt, 32, DDIM, 0, 0, 0);
  // scores[b] = exp(out_att[b] @ out[b]^T) (bf16) + rowsum atomics ; 4*8*8 = 256
  gemm_bt<1, false><<<256, 512, 0, stream>>>(
      oatt, out_b, nullptr, rowsum, scores, 4, SEQ, bs, bs, bs);
  // out2[b] = (scores[b] @ out[b]) / rowsum
  gemm_bt<2, false><<<256, 512, 0, stream>>>(
      scores, outT, nullptr, rowsum, out2, 4, SEQ, bs, bs, bs);
  // em = [p_cla | out2] @ W_hid + b_hid
  em_kernel<<<2048, 256, 0, stream>>>(out2, p_cla, W_hid, b_hid, em);
  // CRF NLL
  crf_kernel<<<NB, 256, 0, stream>>>(em, tags, cstart, cend, ctrans, part);
  final_sum<<<1, 64, 0, stream>>>(part, (float*)d_out);
}

// Round 7
// 165.081 us; speedup vs baseline: 1.3013x; 1.0014x over previous
//
#include <hip/hip_runtime.h>
#include <stdint.h>

typedef unsigned short u16;
typedef __attribute__((ext_vector_type(8))) short bf16x8;
typedef __attribute__((ext_vector_type(4))) float f32x4;

#define NB 8
#define SEQ 1024
#define DDIM 1024
#define NP 128
#define NT 8
#define GK 1024           // K for all GEMMs
#define NKT 16            // GK/64

__device__ __forceinline__ u16 f2b(float f){
  union { float f; uint32_t u; } v; v.f = f;
  return (u16)((v.u + 0x7FFFu + ((v.u >> 16) & 1u)) >> 16);
}
__device__ __forceinline__ float b2f(u16 h){
  union { uint32_t u; float f; } v; v.u = ((uint32_t)h) << 16; return v.f;
}

__device__ __forceinline__ void load_lds16(const void* g, void* l){
  __builtin_amdgcn_global_load_lds((const __attribute__((address_space(1))) void*)g,
                                   (__attribute__((address_space(3))) void*)l,
                                   16, 0, 0);
}

#define MEMFENCE asm volatile("" ::: "memory")
#define SBAR() do { MEMFENCE; __builtin_amdgcn_s_barrier(); MEMFENCE; } while(0)

// ------- merged prep: f32->bf16 convert of x + 2 weight transposes + rowsum/d_out zero -------
__global__ __launch_bounds__(256) void prep_kernel(const float* __restrict__ x,
                                                   u16* __restrict__ xb,
                                                   const float* __restrict__ W0,
                                                   const float* __restrict__ W1,
                                                   u16* __restrict__ T0,
                                                   u16* __restrict__ T1,
                                                   float* __restrict__ rowsum,
                                                   float* __restrict__ dout){
  __shared__ float tile[32][33];
  const int bid = blockIdx.x;
  const int tid = threadIdx.x;
  if(bid < 8192){
    int idx = (bid * 256 + tid) * 4;
    float4 v = *(const float4*)(x + idx);
    ushort4 o;
    o.x = f2b(v.x); o.y = f2b(v.y); o.z = f2b(v.z); o.w = f2b(v.w);
    *(ushort4*)(xb + idx) = o;
  } else {
    const int b2 = bid - 8192;                 // 0..2047
    const int z  = b2 >> 10;                   // 0/1 -> which weight
    const int bx = b2 & 31, by = (b2 >> 5) & 31;
    const int tx = tid & 31, ty = tid >> 5;    // 32 x 8
    const float* W = z ? W1 : W0;
    u16* Wt = z ? T1 : T0;
    const int c0 = bx * 32, r0 = by * 32;
    for(int i = ty; i < 32; i += 8)
      tile[i][tx] = W[(size_t)(r0 + i) * DDIM + c0 + tx];
    __syncthreads();
    for(int i = ty; i < 32; i += 8)
      Wt[(size_t)(c0 + i) * DDIM + r0 + tx] = f2b(tile[tx][i]);
    if(z == 0 && by == 0)
      rowsum[bx * 256 + tid] = 0.f;
    if(b2 == 0 && tid == 0)
      dout[0] = 0.f;
  }
}

// ============ minimal-barrier pipelined bf16 GEMM: C = epilogue(A[M,1024] . Bt[N,1024]^T) ============
// BM=256 BN=128 BK=64, 8 waves (4Mx2N), TRIPLE-buffered LDS.
// ONE barrier + ONE counted vmcnt per K-tile; waves free-run within the tile.
// XOR-swizzled LDS via pre-swizzled global source; bijective XCD swizzle.
// MODE 0: C = [relu](acc + bias)    -> bf16
// MODE 1: C = exp(acc) -> bf16, rowsum[bz*SEQ+row] += sum_cols exp (atomic)
template<int MODE, bool RELU>
__global__ __launch_bounds__(512, 2) void gemm_bt(
    const u16* __restrict__ A, const u16* __restrict__ Bt,
    const float* __restrict__ bias, float* __restrict__ rowsum,
    u16* __restrict__ Cv,
    int gm, int N, long long bA, long long bB, long long bC)
{
  __shared__ u16 As[3][256][64];   // 96 KB
  __shared__ u16 Bs[3][128][64];   // 48 KB

  const int tid  = threadIdx.x;
  const int lane = tid & 63;
  const int wid  = tid >> 6;   // 0..7
  const int wr   = wid >> 1;   // 0..3 -> M
  const int wc   = wid & 1;    // 0..1 -> N

  // T1: bijective XCD swizzle (gridDim.x % 8 == 0 at all call sites)
  int id = blockIdx.x;
  const int chunk = gridDim.x >> 3;
  id = (id & 7) * chunk + (id >> 3);
  const int tn = id & 7;
  const int tm = (id >> 3) % gm;
  const int bz = (id >> 3) / gm;

  const char* gAp = (const char*)(A  + (size_t)bz * bA + (size_t)tm * 256 * GK);
  const char* gBp = (const char*)(Bt + (size_t)bz * bB + (size_t)tn * 128 * GK);
  const int colg = ((tid & 7) * 16) ^ (((tid >> 3) & 7) << 4);
  const char* gA0 = gAp + (size_t)(tid >> 3) * 2048 + colg;
  const char* gB0 = gBp + (size_t)(tid >> 3) * 2048 + colg;
  char* lA0 = (char*)&As[0][0][0] + tid * 16;
  char* lB0 = (char*)&Bs[0][0][0] + tid * 16;
  const int SLA = 256 * 64 * 2;   // bytes per A slot
  const int SLB = 128 * 64 * 2;

  auto stageA = [&](int slot, int tt){   // 4 loads
    const int g = tt * 128;
#pragma unroll
    for(int q = 0; q < 4; q++)
      load_lds16(gA0 + (size_t)q * 64 * 2048 + g, lA0 + slot * SLA + q * 8192);
  };
  auto stageB = [&](int slot, int tt){   // 2 loads
    const int g = tt * 128;
#pragma unroll
    for(int q = 0; q < 2; q++)
      load_lds16(gB0 + (size_t)q * 64 * 2048 + g, lB0 + slot * SLB + q * 8192);
  };

  f32x4 acc[4][4];
#pragma unroll
  for(int i = 0; i < 4; i++)
#pragma unroll
    for(int j = 0; j < 4; j++){ acc[i][j][0]=0.f; acc[i][j][1]=0.f; acc[i][j][2]=0.f; acc[i][j][3]=0.f; }

  const int fr = lane & 15, kq = lane >> 4;
  const int a0 = (kq * 16) ^ ((fr & 7) << 4);   // ks=0 byte offset within 128B row
  const int a1 = a0 ^ 64;                       // ks=1
  const char* aRd = (const char*)&As[0][0][0] + (wr * 64 + fr) * 128;
  const char* bRd = (const char*)&Bs[0][0][0] + (wc * 64 + fr) * 128;

  // ---- prologue: stage tiles 0,1 (12 loads in flight) ----
  stageA(0, 0); stageB(0, 0);
  stageA(1, 1); stageB(1, 1);

  int slot = 0, slotp = 2;   // slotp = (t+2)%3
  for(int t = 0; t < NKT; ++t){
    if(t < NKT - 1){ asm volatile("s_waitcnt vmcnt(6)" ::: "memory"); }
    else           { asm volatile("s_waitcnt vmcnt(0)" ::: "memory"); }
    SBAR();   // collective: tile t staged for ALL waves; tile t-1 reads all done

    const char* ab = aRd + slot * SLA;
    const char* bb = bRd + slot * SLB;
    bf16x8 av[4], bv[4], aw[4], bw[4];
#pragma unroll
    for(int mi = 0; mi < 4; mi++) av[mi] = *(const bf16x8*)(ab + mi * 2048 + a0);
#pragma unroll
    for(int ni = 0; ni < 4; ni++) bv[ni] = *(const bf16x8*)(bb + ni * 2048 + a0);
#pragma unroll
    for(int mi = 0; mi < 4; mi++) aw[mi] = *(const bf16x8*)(ab + mi * 2048 + a1);
#pragma unroll
    for(int ni = 0; ni < 4; ni++) bw[ni] = *(const bf16x8*)(bb + ni * 2048 + a1);
    if(t + 2 < NKT){ stageA(slotp, t + 2); stageB(slotp, t + 2); }

    __builtin_amdgcn_s_setprio(1);
#pragma unroll
    for(int mi = 0; mi < 4; mi++)
#pragma unroll
      for(int ni = 0; ni < 4; ni++)
        acc[mi][ni] = __builtin_amdgcn_mfma_f32_16x16x32_bf16(av[mi], bv[ni], acc[mi][ni], 0, 0, 0);
#pragma unroll
    for(int mi = 0; mi < 4; mi++)
#pragma unroll
      for(int ni = 0; ni < 4; ni++)
        acc[mi][ni] = __builtin_amdgcn_mfma_f32_16x16x32_bf16(aw[mi], bw[ni], acc[mi][ni], 0, 0, 0);
    __builtin_amdgcn_s_setprio(0);

    slot  = (slot  == 2) ? 0 : slot  + 1;
    slotp = (slotp == 2) ? 0 : slotp + 1;
  }

  // ---- epilogue: C/D layout col=lane&15, row=(lane>>4)*4+reg ----
  const int m0 = tm * 256 + wr * 64;
  const int n0 = tn * 128 + wc * 64;
  const int rq = lane >> 4;

  if(MODE == 0){
#pragma unroll
    for(int ni = 0; ni < 4; ni++){
      const int gcol = n0 + ni * 16 + fr;
      const float bv = bias[gcol];
#pragma unroll
      for(int mi = 0; mi < 4; mi++){
#pragma unroll
        for(int r = 0; r < 4; r++){
          const int grow = m0 + mi * 16 + rq * 4 + r;
          float v = acc[mi][ni][r] + bv;
          if(RELU) v = fmaxf(v, 0.f);
          Cv[(size_t)bz * bC + (size_t)grow * N + gcol] = f2b(v);
        }
      }
    }
  } else {
    float rs[4][4];
#pragma unroll
    for(int mi = 0; mi < 4; mi++)
#pragma unroll
      for(int r = 0; r < 4; r++) rs[mi][r] = 0.f;
#pragma unroll
    for(int ni = 0; ni < 4; ni++){
      const int gcol = n0 + ni * 16 + fr;
#pragma unroll
      for(int mi = 0; mi < 4; mi++){
#pragma unroll
        for(int r = 0; r < 4; r++){
          const int grow = m0 + mi * 16 + rq * 4 + r;
          float e = __expf(acc[mi][ni][r]);
          rs[mi][r] += e;
          Cv[(size_t)bz * bC + (size_t)grow * N + gcol] = f2b(e);
        }
      }
    }
#pragma unroll
    for(int off = 1; off < 16; off <<= 1)
#pragma unroll
      for(int mi = 0; mi < 4; mi++)
#pragma unroll
        for(int r = 0; r < 4; r++) rs[mi][r] += __shfl_xor(rs[mi][r], off);
    if(fr == 0){
#pragma unroll
      for(int mi = 0; mi < 4; mi++)
#pragma unroll
        for(int r = 0; r < 4; r++){
          const int grow = m0 + mi * 16 + rq * 4 + r;
          atomicAdd(&rowsum[bz * SEQ + grow], rs[mi][r]);
        }
    }
  }
}

// ---------------- VW[b][t][j] = sum_d out_b[b][t][d] * W_hid[NP+d][j] ----------------
// wave per (b,t) row; lane covers 16 d's; shuffle-reduce over 64 lanes.
__global__ __launch_bounds__(256) void vw_kernel(const u16* __restrict__ outb,
                                                 const float* __restrict__ Whid,
                                                 float* __restrict__ VW){
  const int row  = blockIdx.x * 4 + (threadIdx.x >> 6);   // 0..8191 = b*1024+t
  const int lane = threadIdx.x & 63;
  float s[8] = {0.f,0.f,0.f,0.f,0.f,0.f,0.f,0.f};
  const u16* o = outb + (size_t)row * 1024 + lane * 16;
#pragma unroll
  for(int h = 0; h < 2; h++){
    bf16x8 v = *(const bf16x8*)(o + h * 8);
#pragma unroll
    for(int e = 0; e < 8; e++){
      const float od = b2f((u16)v[e]);
      const int d = lane * 16 + h * 8 + e;
      const float* wr = Whid + (size_t)(NP + d) * 8;
#pragma unroll
      for(int j = 0; j < 8; j++) s[j] += od * wr[j];
    }
  }
#pragma unroll
  for(int off = 1; off < 64; off <<= 1)
#pragma unroll
    for(int j = 0; j < 8; j++) s[j] += __shfl_xor(s[j], off);
  if(lane == 0){
#pragma unroll
    for(int j = 0; j < 8; j++) VW[(size_t)row * 8 + j] = s[j];
  }
}

// ------- em[row][j] = b_hid[j] + p_cla[row]@W_hidP + (P[row] @ VW[bz]) / rowsum[row] -------
// wave per row; P = unnormalized exp scores (bf16).
__global__ __launch_bounds__(256) void em2_kernel(const u16* __restrict__ scores,
                                                  const float* __restrict__ pcla,
                                                  const float* __restrict__ VW,
                                                  const float* __restrict__ rowsum,
                                                  const float* __restrict__ Whid,
                                                  const float* __restrict__ bhid,
                                                  float* __restrict__ em){
  const int row  = blockIdx.x * 4 + (threadIdx.x >> 6);   // 0..8191
  const int lane = threadIdx.x & 63;
  const int bz   = row >> 10;
  float sa[8] = {0.f,0.f,0.f,0.f,0.f,0.f,0.f,0.f};   // attention part (to be /rowsum)
  float sp[8] = {0.f,0.f,0.f,0.f,0.f,0.f,0.f,0.f};   // p_cla part
  const u16* pr = scores + (size_t)row * 1024 + lane * 16;
  const float* vwb = VW + (size_t)bz * 8192;
#pragma unroll
  for(int h = 0; h < 2; h++){
    bf16x8 v = *(const bf16x8*)(pr + h * 8);
#pragma unroll
    for(int e = 0; e < 8; e++){
      const float pv = b2f((u16)v[e]);
      const int t = lane * 16 + h * 8 + e;
      const float* vr = vwb + (size_t)t * 8;
#pragma unroll
      for(int j = 0; j < 8; j++) sa[j] += pv * vr[j];
    }
  }
#pragma unroll
  for(int q = 0; q < 2; q++){
    const int p = lane * 2 + q;
    const float pv = pcla[(size_t)row * NP + p];
    const float* wr = Whid + (size_t)p * 8;
#pragma unroll
    for(int j = 0; j < 8; j++) sp[j] += pv * wr[j];
  }
#pragma unroll
  for(int off = 1; off < 64; off <<= 1)
#pragma unroll
    for(int j = 0; j < 8; j++){
      sa[j] += __shfl_xor(sa[j], off);
      sp[j] += __shfl_xor(sp[j], off);
    }
  if(lane == 0){
    const float inv = 1.f / rowsum[row];
#pragma unroll
    for(int j = 0; j < 8; j++)
      em[(size_t)row * 8 + j] = sa[j] * inv + sp[j] + bhid[j];
  }
}

// ---------------- CRF NLL per batch (prob-domain chunked scan + tree) ----------------
__global__ __launch_bounds__(256) void crf_kernel(const float* __restrict__ em,
                                                  const int* __restrict__ tags,
                                                  const float* __restrict__ cstart,
                                                  const float* __restrict__ cend,
                                                  const float* __restrict__ ctrans,
                                                  float* __restrict__ out){
  const int b = blockIdx.x;
  const int tid = threadIdx.x;
  const float* emb = em + (size_t)b * SEQ * 8;
  const int* tg = tags + b * SEQ;

  __shared__ float Mbuf[128][64];
  __shared__ float Mbuf2[64][64];
  __shared__ float ls1[128], ls2[64];
  __shared__ float etr_s[64];
  __shared__ float mxs[64];
  __shared__ float red[256];

  if(tid < 64) etr_s[tid] = expf(ctrans[tid]);

  float loc = 0.f;
  for(int t = tid; t < SEQ; t += 256){
    const int tgt = tg[t];
    loc += emb[t * 8 + tgt];
    if(t < SEQ - 1) loc += ctrans[tgt * 8 + tg[t + 1]];
  }
  if(tid == 0) loc += cstart[tg[0]] + cend[tg[SEQ - 1]];
  red[tid] = loc;
  __syncthreads();
  for(int s = 128; s > 0; s >>= 1){
    if(tid < s) red[tid] += red[tid + s];
    __syncthreads();
  }

  if(tid < 128){
    const int c = tid;
    const int t0 = (c == 0) ? 1 : c * 8;
    const int t1 = c * 8 + 8;
    float etr[64];
#pragma unroll
    for(int i = 0; i < 64; i++) etr[i] = etr_s[i];
    float acc[64];
    float ej[8];
#pragma unroll
    for(int j = 0; j < 8; j++) ej[j] = expf(emb[t0 * 8 + j]);
#pragma unroll
    for(int i = 0; i < 8; i++)
#pragma unroll
      for(int j = 0; j < 8; j++) acc[i * 8 + j] = etr[i * 8 + j] * ej[j];
    for(int t = t0 + 1; t < t1; t++){
#pragma unroll
      for(int j = 0; j < 8; j++) ej[j] = expf(emb[t * 8 + j]);
#pragma unroll
      for(int i = 0; i < 8; i++){
        float tmp[8];
#pragma unroll
        for(int j = 0; j < 8; j++){
          float sv = 0.f;
#pragma unroll
          for(int k = 0; k < 8; k++) sv += acc[i * 8 + k] * etr[k * 8 + j];
          tmp[j] = sv * ej[j];
        }
#pragma unroll
        for(int j = 0; j < 8; j++) acc[i * 8 + j] = tmp[j];
      }
    }
    float mx = acc[0];
#pragma unroll
    for(int i = 1; i < 64; i++) mx = fmaxf(mx, acc[i]);
    const float im = 1.f / mx;
#pragma unroll
    for(int i = 0; i < 64; i++) Mbuf[c][i] = acc[i] * im;
    ls1[c] = logf(mx);
  }
  __syncthreads();

  float* src = &Mbuf[0][0];  float* dst = &Mbuf2[0][0];
  float* lsrc = ls1;         float* ldst = ls2;
  for(int n = 64; n >= 1; n >>= 1){
    for(int idx = tid; idx < n * 64; idx += 256){
      const int p = idx >> 6, e = idx & 63, i = e >> 3, j = e & 7;
      const float* Am = src + (size_t)(2 * p) * 64;
      const float* Bm = src + (size_t)(2 * p + 1) * 64;
      float sv = 0.f;
#pragma unroll
      for(int k = 0; k < 8; k++) sv += Am[i * 8 + k] * Bm[k * 8 + j];
      dst[(size_t)p * 64 + e] = sv;
    }
    __syncthreads();
    if(tid < n){
      const float* Cm = dst + (size_t)tid * 64;
      float mx = Cm[0];
#pragma unroll
      for(int i = 1; i < 64; i++) mx = fmaxf(mx, Cm[i]);
      mxs[tid] = 1.f / mx;
      ldst[tid] = lsrc[2 * tid] + lsrc[2 * tid + 1] + logf(mx);
    }
    __syncthreads();
    for(int idx = tid; idx < n * 64; idx += 256)
      dst[idx] *= mxs[idx >> 6];
    __syncthreads();
    float* tf = src; src = dst; dst = tf;
    float* tl = lsrc; lsrc = ldst; ldst = tl;
  }

  if(tid == 0){
    float a0[8];
#pragma unroll
    for(int i = 0; i < 8; i++) a0[i] = expf(cstart[i] + emb[i]);
    float z = 0.f;
#pragma unroll
    for(int j = 0; j < 8; j++){
      float t = 0.f;
#pragma unroll
      for(int i = 0; i < 8; i++) t += a0[i] * src[i * 8 + j];
      z += t * expf(cend[j]);
    }
    const float logZ = logf(z) + lsrc[0];
    atomicAdd(out, logZ - red[0]);
  }
}

// ---------------- launch ----------------
extern "C" void kernel_launch(void* const* d_in, const int* in_sizes, int n_in,
                              void* d_out, int out_size, void* d_ws, size_t ws_size,
                              hipStream_t stream){
  (void)in_sizes; (void)n_in; (void)out_size; (void)ws_size;
  const float* x      = (const float*)d_in[0];
  const float* p_cla  = (const float*)d_in[1];
  const float* W_emo  = (const float*)d_in[2];
  const float* b_emo  = (const float*)d_in[3];
  const float* W_att  = (const float*)d_in[4];
  const float* b_att  = (const float*)d_in[5];
  const float* W_hid  = (const float*)d_in[6];
  const float* b_hid  = (const float*)d_in[7];
  const float* cstart = (const float*)d_in[8];
  const float* cend   = (const float*)d_in[9];
  const float* ctrans = (const float*)d_in[10];
  const int*   tags   = (const int*)d_in[11];

  char* ws = (char*)d_ws;
  const size_t MB = 1u << 20;
  u16*   xb     = (u16*)(ws + 0 * MB);        // 16MB
  u16*   wemoT  = (u16*)(ws + 16 * MB);       // 2MB
  u16*   wattT  = (u16*)(ws + 18 * MB);       // 2MB
  u16*   out_b  = (u16*)(ws + 20 * MB);       // 16MB
  u16*   oatt   = (u16*)(ws + 36 * MB);       // 16MB
  u16*   scores = (u16*)(ws + 52 * MB);       // 16MB (unnormalized exp, bf16)
  float* VW     = (float*)(ws + 68 * MB);     // 256KB
  float* em     = (float*)(ws + 69 * MB);     // 256KB
  float* rowsum = (float*)(ws + 70 * MB);     // 32KB

  const long long bs = (long long)SEQ * DDIM;

  // convert x + transpose both weights + zero rowsum/d_out, one launch
  prep_kernel<<<8192 + 2048, 256, 0, stream>>>(x, xb, W_emo, W_att, wemoT, wattT,
                                               rowsum, (float*)d_out);

  // out = relu(x @ W_emo + b_emo) ; grid = 32*8 = 256
  gemm_bt<0, true><<<256, 512, 0, stream>>>(
      xb, wemoT, b_emo, nullptr, out_b, 32, DDIM, 0, 0, 0);
  // out_att = out @ W_att + b_att
  gemm_bt<0, false><<<256, 512, 0, stream>>>(
      out_b, wattT, b_att, nullptr, oatt, 32, DDIM, 0, 0, 0);
  // scores[b] = exp(out_att[b] @ out[b]^T) (bf16) + rowsum atomics ; 4*8*8 = 256
  gemm_bt<1, false><<<256, 512, 0, stream>>>(
      oatt, out_b, nullptr, rowsum, scores, 4, SEQ, bs, bs, bs);
  // VW[b] = out[b] @ W_hid[NP:,:]  (skinny)
  vw_kernel<<<2048, 256, 0, stream>>>(out_b, W_hid, VW);
  // em = b_hid + p_cla@W_hid[:NP,:] + (P @ VW)/rowsum   (replaces GEMM4 + em)
  em2_kernel<<<2048, 256, 0, stream>>>(scores, p_cla, VW, rowsum, W_hid, b_hid, em);
  // CRF NLL -> atomicAdd into d_out (zeroed by prep)
  crf_kernel<<<NB, 256, 0, stream>>>(em, tags, cstart, cend, ctrans, (float*)d_out);
}